// Round 13
// baseline (357.409 us; speedup 1.0000x reference)
//
#include <hip/hip_runtime.h>
#include <cstdint>
#include <cstddef>

typedef unsigned short u16;
typedef __attribute__((ext_vector_type(8))) short short8;
typedef __attribute__((ext_vector_type(4))) float f32x4;
typedef __attribute__((ext_vector_type(4))) unsigned short us4;

#define AS1 __attribute__((address_space(1)))
#define AS3 __attribute__((address_space(3)))

__device__ __forceinline__ u16 f2bf(float f) {
  union { float f; unsigned u; } v; v.f = f;
  unsigned r = v.u + 0x7fffu + ((v.u >> 16) & 1u);
  return (u16)(r >> 16);
}

__device__ __forceinline__ void gload_lds16(const u16* g, u16* l) {
  __builtin_amdgcn_global_load_lds((AS1 void*)g, (AS3 void*)l, 16, 0, 0);
}

// ---------------- LayerNorm + cast to bf16 (token-major) ----------------
__global__ void ln_cast_kernel(const float* __restrict__ x, const float* __restrict__ g,
                               const float* __restrict__ b, u16* __restrict__ out) {
  const int lane = threadIdx.x & 63;
  const int tok = blockIdx.x * 4 + (threadIdx.x >> 6);
  const float4* row = (const float4*)(x + (size_t)tok * 512);
  float4 v0 = row[lane];
  float4 v1 = row[lane + 64];
  float s = v0.x + v0.y + v0.z + v0.w + v1.x + v1.y + v1.z + v1.w;
  float q = v0.x*v0.x + v0.y*v0.y + v0.z*v0.z + v0.w*v0.w
          + v1.x*v1.x + v1.y*v1.y + v1.z*v1.z + v1.w*v1.w;
#pragma unroll
  for (int m = 1; m < 64; m <<= 1) { s += __shfl_xor(s, m, 64); q += __shfl_xor(q, m, 64); }
  const float mean = s * (1.0f / 512.0f);
  const float var = q * (1.0f / 512.0f) - mean * mean;
  const float r = rsqrtf(var + 1e-5f);
  const float4* g4 = (const float4*)g;
  const float4* b4 = (const float4*)b;
  float4 ga = g4[lane], gb = g4[lane + 64];
  float4 ba = b4[lane], bb = b4[lane + 64];
  us4 o0 = { f2bf((v0.x - mean) * r * ga.x + ba.x), f2bf((v0.y - mean) * r * ga.y + ba.y),
             f2bf((v0.z - mean) * r * ga.z + ba.z), f2bf((v0.w - mean) * r * ga.w + ba.w) };
  us4 o1 = { f2bf((v1.x - mean) * r * gb.x + bb.x), f2bf((v1.y - mean) * r * gb.y + bb.y),
             f2bf((v1.z - mean) * r * gb.z + bb.z), f2bf((v1.w - mean) * r * gb.w + bb.w) };
  *(us4*)(out + (size_t)tok * 512 + lane * 4) = o0;
  *(us4*)(out + (size_t)tok * 512 + 256 + lane * 4) = o1;
}

// ---------------- weight transpose + cast ----------------
__global__ void prep_w_kernel(const float* __restrict__ wqkv, const float* __restrict__ wout,
                              u16* __restrict__ wqkvT, u16* __restrict__ woutT) {
  int idx = blockIdx.x * blockDim.x + threadIdx.x;
  if (idx < 512 * 1536) {
    int n = idx >> 9, k = idx & 511;
    wqkvT[idx] = f2bf(wqkv[k * 1536 + n]);
  } else {
    int j = idx - 512 * 1536;
    if (j < 512 * 512) {
      int n = j >> 9, k = j & 511;
      woutT[j] = f2bf(wout[k * 512 + n]);
    }
  }
}

// ---------------- DPB MLP ----------------
__device__ __forceinline__ float lnrelu128(float a, float g, float* red, int tid) {
  float s = a, q = a * a;
#pragma unroll
  for (int m = 1; m < 64; m <<= 1) { s += __shfl_xor(s, m, 64); q += __shfl_xor(q, m, 64); }
  __syncthreads();
  if ((tid & 63) == 0) { red[tid >> 6] = s; red[2 + (tid >> 6)] = q; }
  __syncthreads();
  float S = red[0] + red[1], Q = red[2] + red[3];
  float mean = S * (1.f / 128.f);
  float var = Q * (1.f / 128.f) - mean * mean;
  float y = (a - mean) * rsqrtf(var + 1e-5f) * g;
  return fmaxf(y, 0.f);
}

__global__ void dpb_mlp_kernel(const float* __restrict__ w0, const float* __restrict__ b0, const float* __restrict__ g0,
                               const float* __restrict__ w1, const float* __restrict__ b1, const float* __restrict__ g1,
                               const float* __restrict__ w2, const float* __restrict__ b2, const float* __restrict__ g2,
                               const float* __restrict__ w3, const float* __restrict__ b3,
                               float* __restrict__ biases) {
  __shared__ float h[128];
  __shared__ float red[4];
  const int tid = threadIdx.x;
  const int row = blockIdx.x;
  const float p0 = (float)(row / 17) - 8.0f;
  const float p1 = (float)(row % 17) - 8.0f;
  float a = p0 * w0[tid] + p1 * w0[128 + tid] + b0[tid];
  a = lnrelu128(a, g0[tid], red, tid);
  h[tid] = a;
  __syncthreads();
  float acc = b1[tid];
  for (int i = 0; i < 128; ++i) acc += h[i] * w1[i * 128 + tid];
  acc = lnrelu128(acc, g1[tid], red, tid);
  h[tid] = acc;
  __syncthreads();
  float acc2 = b2[tid];
  for (int i = 0; i < 128; ++i) acc2 += h[i] * w2[i * 128 + tid];
  acc2 = lnrelu128(acc2, g2[tid], red, tid);
  float t = acc2 * w3[tid];
#pragma unroll
  for (int m = 1; m < 64; m <<= 1) t += __shfl_xor(t, m, 64);
  __syncthreads();
  if ((tid & 63) == 0) red[tid >> 6] = t;
  __syncthreads();
  if (tid == 0) biases[row] = red[0] + red[1] + b3[0];
}

__global__ void dpb_table_kernel(const float* __restrict__ biases, float* __restrict__ table) {
  int t = blockIdx.x * blockDim.x + threadIdx.x;
  if (t < 4096) {
    int i = t >> 6, j = t & 63;
    int r0 = (i >> 3) - (j >> 3) + 7;
    int r1 = (i & 7) - (j & 7) + 7;
    table[t] = biases[r0 * 15 + r1];
  }
}

// ---------------- 128x128 bf16 GEMM, BK=64, 4 blocks/CU (round-10, verified 129.5us) ----------------
template <int CT, bool F32OUT>
__global__ __launch_bounds__(256, 4) void gemm_bk64_kernel(const u16* __restrict__ A, const u16* __restrict__ BT,
                                                           void* __restrict__ Cv, const float* __restrict__ bias) {
  __shared__ __align__(16) u16 As[128 * 64];
  __shared__ __align__(16) u16 Bs[128 * 64];
  const int tid = threadIdx.x;
  const int w = tid >> 6, l = tid & 63;
  const int wr = w >> 1, wc = w & 1;
  const int cr = l & 15, cg = l >> 4;
  const int hcr = (cr + ((cr >> 3) << 2)) & 7;   // read-side swizzle (lane-constant)

  // XCD-affine remap: CT col-tiles of one A row-panel share an XCD.
  const int hw = blockIdx.x;
  const int ix = hw >> 3;
  const int rt = (hw & 7) + 8 * (ix / CT);
  const int ct = ix % CT;
  const size_t brow = (size_t)rt * 128;
  const size_t bcol = (size_t)ct * 128;
  const int N = CT * 128;

  const int srow8 = tid >> 3;
  const int hsrc = ((srow8 & 15) + (((srow8 >> 3) & 1) << 2)) & 7;
  const int csrc = ((tid & 7) ^ hsrc) * 8;
  const u16* gA = A + (brow + srow8) * 512 + csrc;
  const u16* gB = BT + (bcol + srow8) * 512 + csrc;

  const f32x4 zero = {0.f, 0.f, 0.f, 0.f};
  f32x4 acc[4][4];
#pragma unroll
  for (int i = 0; i < 4; ++i)
#pragma unroll
    for (int j = 0; j < 4; ++j) acc[i][j] = zero;

  const u16* aP = &As[(wr * 64 + cr) * 64];
  const u16* bP = &Bs[(wc * 64 + cr) * 64];

  for (int k0 = 0; k0 < 512; k0 += 64) {
#pragma unroll
    for (int j = 0; j < 4; ++j) {
      gload_lds16(gA + (size_t)j * 32 * 512 + k0, &As[j * 2048 + w * 512]);
      gload_lds16(gB + (size_t)j * 32 * 512 + k0, &Bs[j * 2048 + w * 512]);
    }
    __syncthreads();
#pragma unroll
    for (int ks = 0; ks < 2; ++ks) {
      short8 af[4], bf[4];
      const int pco = ((ks * 4 + cg) ^ hcr) * 8;
#pragma unroll
      for (int fr = 0; fr < 4; ++fr) af[fr] = *(const short8*)(aP + fr * 1024 + pco);
#pragma unroll
      for (int fc = 0; fc < 4; ++fc) bf[fc] = *(const short8*)(bP + fc * 1024 + pco);
#pragma unroll
      for (int fr = 0; fr < 4; ++fr)
#pragma unroll
        for (int fc = 0; fc < 4; ++fc)
          acc[fr][fc] = __builtin_amdgcn_mfma_f32_16x16x32_bf16(bf[fc], af[fr], acc[fr][fc], 0, 0, 0);
    }
    __syncthreads();
  }

  if (F32OUT) {
    float* C = (float*)Cv;
#pragma unroll
    for (int fc = 0; fc < 4; ++fc) {
      size_t col = bcol + wc * 64 + fc * 16 + cg * 4;
      float4 bv = *(const float4*)&bias[col];
#pragma unroll
      for (int fr = 0; fr < 4; ++fr) {
        size_t r = brow + wr * 64 + fr * 16 + cr;
        float4 o = { acc[fr][fc][0] + bv.x, acc[fr][fc][1] + bv.y,
                     acc[fr][fc][2] + bv.z, acc[fr][fc][3] + bv.w };
        *(float4*)(C + r * N + col) = o;
      }
    }
  } else {
    u16* C = (u16*)Cv;
#pragma unroll
    for (int fc = 0; fc < 4; ++fc) {
      size_t col = bcol + wc * 64 + fc * 16 + cg * 4;
#pragma unroll
      for (int fr = 0; fr < 4; ++fr) {
        size_t r = brow + wr * 64 + fr * 16 + cr;
        uint2 p;
        p.x = (unsigned)f2bf(acc[fr][fc][0]) | ((unsigned)f2bf(acc[fr][fc][1]) << 16);
        p.y = (unsigned)f2bf(acc[fr][fc][2]) | ((unsigned)f2bf(acc[fr][fc][3]) << 16);
        *(uint2*)(C + r * N + col) = p;
      }
    }
  }
}

// ---------------- windowed attention v2 (round-9, verified): 4 waves/block, in-register softmax ----------------
__global__ __launch_bounds__(256, 3) void attn_kernel(const u16* __restrict__ qkv,
                                                      const float* __restrict__ table,
                                                      u16* __restrict__ aout) {
  __shared__ __align__(16) u16 VT[4][32 * 72];
  const int l = threadIdx.x & 63;
  const int wv = threadIdx.x >> 6;
  const int pair = blockIdx.x * 4 + wv;
  const int head = pair & 15;
  const int win = pair >> 4;
  const int base = ((win >> 6) << 12) + (((win >> 3) & 7) << 9) + ((win & 7) << 3);
  const int cr = l & 15, cg = l >> 4;
  u16* vt = VT[wv];

  {
    const size_t row = base + ((l >> 3) << 6) + (l & 7);
    const u16* vp = qkv + row * 1536 + 1024 + head * 32;
    short8 v0 = *(const short8*)(vp);
    short8 v1 = *(const short8*)(vp + 8);
    short8 v2 = *(const short8*)(vp + 16);
    short8 v3 = *(const short8*)(vp + 24);
#pragma unroll
    for (int j = 0; j < 8; ++j) {
      vt[j * 72 + l] = (u16)v0[j];
      vt[(8 + j) * 72 + l] = (u16)v1[j];
      vt[(16 + j) * 72 + l] = (u16)v2[j];
      vt[(24 + j) * 72 + l] = (u16)v3[j];
    }
  }

  short8 qf[4], kf[4];
#pragma unroll
  for (int i = 0; i < 4; ++i) {
    int t = i * 16 + cr;
    size_t row = base + ((t >> 3) << 6) + (t & 7);
    qf[i] = *(const short8*)(qkv + row * 1536 + head * 32 + cg * 8);
    kf[i] = *(const short8*)(qkv + row * 1536 + 512 + head * 32 + cg * 8);
  }

  const f32x4 zero = {0.f, 0.f, 0.f, 0.f};
  f32x4 s[4][4];
#pragma unroll
  for (int mt = 0; mt < 4; ++mt)
#pragma unroll
    for (int nt = 0; nt < 4; ++nt)
      s[mt][nt] = __builtin_amdgcn_mfma_f32_16x16x32_bf16(kf[mt], qf[nt], zero, 0, 0, 0);

  asm volatile("s_waitcnt lgkmcnt(0)" ::: "memory");
  __builtin_amdgcn_sched_barrier(0);
  short8 vfT[2][2];
#pragma unroll
  for (int dt = 0; dt < 2; ++dt)
#pragma unroll
    for (int kk = 0; kk < 2; ++kk)
      vfT[dt][kk] = *(const short8*)&vt[(dt * 16 + cr) * 72 + kk * 32 + cg * 8];

  const float scale = 0.17677669529663689f;
  f32x4 o[2][4];
#pragma unroll
  for (int dt = 0; dt < 2; ++dt)
#pragma unroll
    for (int nt = 0; nt < 4; ++nt) o[dt][nt] = zero;

  const int laneA = cr + 32 * (cg & 1);
  const int hi = cg >> 1;

#pragma unroll
  for (int nt = 0; nt < 4; ++nt) {
    float p[16];
    float mx = -3.0e38f;
#pragma unroll
    for (int mt = 0; mt < 4; ++mt) {
      float4 tb = *(const float4*)&table[(nt * 16 + cr) * 64 + mt * 16 + cg * 4];
      p[mt * 4 + 0] = s[mt][nt][0] * scale + tb.x;
      p[mt * 4 + 1] = s[mt][nt][1] * scale + tb.y;
      p[mt * 4 + 2] = s[mt][nt][2] * scale + tb.z;
      p[mt * 4 + 3] = s[mt][nt][3] * scale + tb.w;
      mx = fmaxf(mx, fmaxf(fmaxf(p[mt * 4], p[mt * 4 + 1]), fmaxf(p[mt * 4 + 2], p[mt * 4 + 3])));
    }
    mx = fmaxf(mx, __shfl_xor(mx, 16, 64));
    mx = fmaxf(mx, __shfl_xor(mx, 32, 64));
    float sum = 0.f;
#pragma unroll
    for (int i = 0; i < 16; ++i) { p[i] = __expf(p[i] - mx); sum += p[i]; }
    sum += __shfl_xor(sum, 16, 64);
    sum += __shfl_xor(sum, 32, 64);
    const float inv = 1.0f / sum;

    unsigned pk[4][2];
#pragma unroll
    for (int mt = 0; mt < 4; ++mt)
#pragma unroll
      for (int i = 0; i < 2; ++i)
        pk[mt][i] = (unsigned)f2bf(p[mt * 4 + 2 * i] * inv) | ((unsigned)f2bf(p[mt * 4 + 2 * i + 1] * inv) << 16);

#pragma unroll
    for (int kk = 0; kk < 2; ++kk) {
      union { unsigned u[4]; short8 v; } pf;
#pragma unroll
      for (int i = 0; i < 2; ++i) {
        unsigned x0 = (unsigned)__shfl((int)pk[2 * kk][i], laneA, 64);
        unsigned x1 = (unsigned)__shfl((int)pk[2 * kk + 1][i], laneA, 64);
        unsigned y0 = (unsigned)__shfl((int)pk[2 * kk][i], laneA + 16, 64);
        unsigned y1 = (unsigned)__shfl((int)pk[2 * kk + 1][i], laneA + 16, 64);
        pf.u[i] = hi ? x1 : x0;
        pf.u[2 + i] = hi ? y1 : y0;
      }
#pragma unroll
      for (int dt = 0; dt < 2; ++dt)
        o[dt][nt] = __builtin_amdgcn_mfma_f32_16x16x32_bf16(vfT[dt][kk], pf.v, o[dt][nt], 0, 0, 0);
    }
  }

#pragma unroll
  for (int nt = 0; nt < 4; ++nt) {
    int t = nt * 16 + cr;
    size_t row = base + ((t >> 3) << 6) + (t & 7);
#pragma unroll
    for (int dt = 0; dt < 2; ++dt) {
      uint2 pck;
      pck.x = (unsigned)f2bf(o[dt][nt][0]) | ((unsigned)f2bf(o[dt][nt][1]) << 16);
      pck.y = (unsigned)f2bf(o[dt][nt][2]) | ((unsigned)f2bf(o[dt][nt][3]) << 16);
      *(uint2*)(aout + row * 512 + head * 32 + dt * 16 + cg * 4) = pck;
    }
  }
}

// ---------------- launch ----------------
extern "C" void kernel_launch(void* const* d_in, const int* in_sizes, int n_in,
                              void* d_out, int out_size, void* d_ws, size_t ws_size,
                              hipStream_t stream) {
  const float* x = (const float*)d_in[0];
  const float* norm_g = (const float*)d_in[1];
  const float* norm_b = (const float*)d_in[2];
  const float* w_qkv = (const float*)d_in[3];
  const float* w_out = (const float*)d_in[4];
  const float* b_out = (const float*)d_in[5];
  const float* dw0 = (const float*)d_in[6];
  const float* db0 = (const float*)d_in[7];
  const float* dg0 = (const float*)d_in[8];
  const float* dw1 = (const float*)d_in[9];
  const float* db1 = (const float*)d_in[10];
  const float* dg1 = (const float*)d_in[11];
  const float* dw2 = (const float*)d_in[12];
  const float* db2 = (const float*)d_in[13];
  const float* dg2 = (const float*)d_in[14];
  const float* dw3 = (const float*)d_in[15];
  const float* db3 = (const float*)d_in[16];

  char* ws = (char*)d_ws;
  size_t off = 0;
  auto take = [&](size_t bytes) { char* p = ws + off; off += (bytes + 255) & ~(size_t)255; return p; };
  u16* xln = (u16*)take(65536ull * 512 * 2);
  u16* wqkvT = (u16*)take(1536 * 512 * 2);
  u16* woutT = (u16*)take(512 * 512 * 2);
  float* biases = (float*)take(289 * 4);
  float* table = (float*)take(4096 * 4);

  ln_cast_kernel<<<16384, 256, 0, stream>>>(x, norm_g, norm_b, xln);
  prep_w_kernel<<<4096, 256, 0, stream>>>(w_qkv, w_out, wqkvT, woutT);
  dpb_mlp_kernel<<<289, 128, 0, stream>>>(dw0, db0, dg0, dw1, db1, dg1, dw2, db2, dg2, dw3, db3, biases);
  dpb_table_kernel<<<16, 256, 0, stream>>>(biases, table);

  size_t rem = (ws_size > off) ? ws_size - off : 0;
  if (rem >= 65536ull * 2048 * 2 + 512) {
    // Round-13 dataflow: ONE full qkv dispatch (6 CU-rounds amortizes dispatch tail;
    // round-10 verified 129.5us) + attn/out chunked x2 (round-12 verified L3-warm
    // producer->consumer reads: qkvbuf 201MB fits L3; attnbuf chunk 33MB hot for out).
    u16* qkvbuf = (u16*)take(65536ull * 1536 * 2);
    u16* attnbuf = (u16*)take(65536ull * 512 * 2);
    gemm_bk64_kernel<12, false><<<(65536 / 128) * 12, 256, 0, stream>>>(xln, wqkvT, (void*)qkvbuf, nullptr);
    for (int c = 0; c < 2; ++c) {
      const u16* qc = qkvbuf + (size_t)c * 32768 * 1536;
      u16* ac = attnbuf + (size_t)c * 32768 * 512;
      attn_kernel<<<(32768 / 64) * 16 / 4, 256, 0, stream>>>(qc, table, ac);
      float* Cc = (float*)d_out + (size_t)c * 32768 * 512;
      gemm_bk64_kernel<4, true><<<(32768 / 128) * 4, 256, 0, stream>>>(ac, woutT, (void*)Cc, b_out);
    }
  } else {
    // fallback: fully chunked (round-12 path)
    int nch = 4;
    if (rem >= 32768ull * 2048 * 2 + 512) nch = 2;
    const int rows = 65536 / nch;
    u16* qkvbuf = (u16*)take((size_t)rows * 1536 * 2);
    u16* attnbuf = (u16*)take((size_t)rows * 512 * 2);
    for (int c = 0; c < nch; ++c) {
      const u16* Ac = xln + (size_t)c * rows * 512;
      gemm_bk64_kernel<12, false><<<(rows / 128) * 12, 256, 0, stream>>>(Ac, wqkvT, (void*)qkvbuf, nullptr);
      attn_kernel<<<(rows / 64) * 16 / 4, 256, 0, stream>>>(qkvbuf, table, attnbuf);
      float* Cc = (float*)d_out + (size_t)c * rows * 512;
      gemm_bk64_kernel<4, true><<<(rows / 128) * 4, 256, 0, stream>>>(attnbuf, woutT, (void*)Cc, b_out);
    }
  }
}

// Round 14
// 341.762 us; speedup vs baseline: 1.0458x; 1.0458x over previous
//
#include <hip/hip_runtime.h>
#include <cstdint>
#include <cstddef>

typedef unsigned short u16;
typedef __attribute__((ext_vector_type(8))) short short8;
typedef __attribute__((ext_vector_type(4))) float f32x4;
typedef __attribute__((ext_vector_type(4))) unsigned short us4;

#define AS1 __attribute__((address_space(1)))
#define AS3 __attribute__((address_space(3)))

__device__ __forceinline__ u16 f2bf(float f) {
  union { float f; unsigned u; } v; v.f = f;
  unsigned r = v.u + 0x7fffu + ((v.u >> 16) & 1u);
  return (u16)(r >> 16);
}

__device__ __forceinline__ void gload_lds16(const u16* g, u16* l) {
  __builtin_amdgcn_global_load_lds((AS1 void*)g, (AS3 void*)l, 16, 0, 0);
}

// ---------------- LayerNorm + cast to bf16 (token-major) ----------------
__global__ void ln_cast_kernel(const float* __restrict__ x, const float* __restrict__ g,
                               const float* __restrict__ b, u16* __restrict__ out) {
  const int lane = threadIdx.x & 63;
  const int tok = blockIdx.x * 4 + (threadIdx.x >> 6);
  const float4* row = (const float4*)(x + (size_t)tok * 512);
  float4 v0 = row[lane];
  float4 v1 = row[lane + 64];
  float s = v0.x + v0.y + v0.z + v0.w + v1.x + v1.y + v1.z + v1.w;
  float q = v0.x*v0.x + v0.y*v0.y + v0.z*v0.z + v0.w*v0.w
          + v1.x*v1.x + v1.y*v1.y + v1.z*v1.z + v1.w*v1.w;
#pragma unroll
  for (int m = 1; m < 64; m <<= 1) { s += __shfl_xor(s, m, 64); q += __shfl_xor(q, m, 64); }
  const float mean = s * (1.0f / 512.0f);
  const float var = q * (1.0f / 512.0f) - mean * mean;
  const float r = rsqrtf(var + 1e-5f);
  const float4* g4 = (const float4*)g;
  const float4* b4 = (const float4*)b;
  float4 ga = g4[lane], gb = g4[lane + 64];
  float4 ba = b4[lane], bb = b4[lane + 64];
  us4 o0 = { f2bf((v0.x - mean) * r * ga.x + ba.x), f2bf((v0.y - mean) * r * ga.y + ba.y),
             f2bf((v0.z - mean) * r * ga.z + ba.z), f2bf((v0.w - mean) * r * ga.w + ba.w) };
  us4 o1 = { f2bf((v1.x - mean) * r * gb.x + bb.x), f2bf((v1.y - mean) * r * gb.y + bb.y),
             f2bf((v1.z - mean) * r * gb.z + bb.z), f2bf((v1.w - mean) * r * gb.w + bb.w) };
  *(us4*)(out + (size_t)tok * 512 + lane * 4) = o0;
  *(us4*)(out + (size_t)tok * 512 + 256 + lane * 4) = o1;
}

// ---------------- weight transpose + cast ----------------
__global__ void prep_w_kernel(const float* __restrict__ wqkv, const float* __restrict__ wout,
                              u16* __restrict__ wqkvT, u16* __restrict__ woutT) {
  int idx = blockIdx.x * blockDim.x + threadIdx.x;
  if (idx < 512 * 1536) {
    int n = idx >> 9, k = idx & 511;
    wqkvT[idx] = f2bf(wqkv[k * 1536 + n]);
  } else {
    int j = idx - 512 * 1536;
    if (j < 512 * 512) {
      int n = j >> 9, k = j & 511;
      woutT[j] = f2bf(wout[k * 512 + n]);
    }
  }
}

// ---------------- DPB MLP ----------------
__device__ __forceinline__ float lnrelu128(float a, float g, float* red, int tid) {
  float s = a, q = a * a;
#pragma unroll
  for (int m = 1; m < 64; m <<= 1) { s += __shfl_xor(s, m, 64); q += __shfl_xor(q, m, 64); }
  __syncthreads();
  if ((tid & 63) == 0) { red[tid >> 6] = s; red[2 + (tid >> 6)] = q; }
  __syncthreads();
  float S = red[0] + red[1], Q = red[2] + red[3];
  float mean = S * (1.f / 128.f);
  float var = Q * (1.f / 128.f) - mean * mean;
  float y = (a - mean) * rsqrtf(var + 1e-5f) * g;
  return fmaxf(y, 0.f);
}

__global__ void dpb_mlp_kernel(const float* __restrict__ w0, const float* __restrict__ b0, const float* __restrict__ g0,
                               const float* __restrict__ w1, const float* __restrict__ b1, const float* __restrict__ g1,
                               const float* __restrict__ w2, const float* __restrict__ b2, const float* __restrict__ g2,
                               const float* __restrict__ w3, const float* __restrict__ b3,
                               float* __restrict__ biases) {
  __shared__ float h[128];
  __shared__ float red[4];
  const int tid = threadIdx.x;
  const int row = blockIdx.x;
  const float p0 = (float)(row / 17) - 8.0f;
  const float p1 = (float)(row % 17) - 8.0f;
  float a = p0 * w0[tid] + p1 * w0[128 + tid] + b0[tid];
  a = lnrelu128(a, g0[tid], red, tid);
  h[tid] = a;
  __syncthreads();
  float acc = b1[tid];
  for (int i = 0; i < 128; ++i) acc += h[i] * w1[i * 128 + tid];
  acc = lnrelu128(acc, g1[tid], red, tid);
  h[tid] = acc;
  __syncthreads();
  float acc2 = b2[tid];
  for (int i = 0; i < 128; ++i) acc2 += h[i] * w2[i * 128 + tid];
  acc2 = lnrelu128(acc2, g2[tid], red, tid);
  float t = acc2 * w3[tid];
#pragma unroll
  for (int m = 1; m < 64; m <<= 1) t += __shfl_xor(t, m, 64);
  __syncthreads();
  if ((tid & 63) == 0) red[tid >> 6] = t;
  __syncthreads();
  if (tid == 0) biases[row] = red[0] + red[1] + b3[0];
}

__global__ void dpb_table_kernel(const float* __restrict__ biases, float* __restrict__ table) {
  int t = blockIdx.x * blockDim.x + threadIdx.x;
  if (t < 4096) {
    int i = t >> 6, j = t & 63;
    int r0 = (i >> 3) - (j >> 3) + 7;
    int r1 = (i & 7) - (j & 7) + 7;
    table[t] = biases[r0 * 15 + r1];
  }
}

// ---------------- 128x128 bf16 GEMM, BK=64, 4 blocks/CU (round-10, verified) ----------------
template <int CT, bool F32OUT>
__global__ __launch_bounds__(256, 4) void gemm_bk64_kernel(const u16* __restrict__ A, const u16* __restrict__ BT,
                                                           void* __restrict__ Cv, const float* __restrict__ bias) {
  __shared__ __align__(16) u16 As[128 * 64];
  __shared__ __align__(16) u16 Bs[128 * 64];
  const int tid = threadIdx.x;
  const int w = tid >> 6, l = tid & 63;
  const int wr = w >> 1, wc = w & 1;
  const int cr = l & 15, cg = l >> 4;
  const int hcr = (cr + ((cr >> 3) << 2)) & 7;   // read-side swizzle (lane-constant)

  // XCD-affine remap: CT col-tiles of one A row-panel share an XCD.
  const int hw = blockIdx.x;
  const int ix = hw >> 3;
  const int rt = (hw & 7) + 8 * (ix / CT);
  const int ct = ix % CT;
  const size_t brow = (size_t)rt * 128;
  const size_t bcol = (size_t)ct * 128;
  const int N = CT * 128;

  const int srow8 = tid >> 3;
  const int hsrc = ((srow8 & 15) + (((srow8 >> 3) & 1) << 2)) & 7;
  const int csrc = ((tid & 7) ^ hsrc) * 8;
  const u16* gA = A + (brow + srow8) * 512 + csrc;
  const u16* gB = BT + (bcol + srow8) * 512 + csrc;

  const f32x4 zero = {0.f, 0.f, 0.f, 0.f};
  f32x4 acc[4][4];
#pragma unroll
  for (int i = 0; i < 4; ++i)
#pragma unroll
    for (int j = 0; j < 4; ++j) acc[i][j] = zero;

  const u16* aP = &As[(wr * 64 + cr) * 64];
  const u16* bP = &Bs[(wc * 64 + cr) * 64];

  for (int k0 = 0; k0 < 512; k0 += 64) {
#pragma unroll
    for (int j = 0; j < 4; ++j) {
      gload_lds16(gA + (size_t)j * 32 * 512 + k0, &As[j * 2048 + w * 512]);
      gload_lds16(gB + (size_t)j * 32 * 512 + k0, &Bs[j * 2048 + w * 512]);
    }
    __syncthreads();
#pragma unroll
    for (int ks = 0; ks < 2; ++ks) {
      short8 af[4], bf[4];
      const int pco = ((ks * 4 + cg) ^ hcr) * 8;
#pragma unroll
      for (int fr = 0; fr < 4; ++fr) af[fr] = *(const short8*)(aP + fr * 1024 + pco);
#pragma unroll
      for (int fc = 0; fc < 4; ++fc) bf[fc] = *(const short8*)(bP + fc * 1024 + pco);
#pragma unroll
      for (int fr = 0; fr < 4; ++fr)
#pragma unroll
        for (int fc = 0; fc < 4; ++fc)
          acc[fr][fc] = __builtin_amdgcn_mfma_f32_16x16x32_bf16(bf[fc], af[fr], acc[fr][fc], 0, 0, 0);
    }
    __syncthreads();
  }

  if (F32OUT) {
    float* C = (float*)Cv;
#pragma unroll
    for (int fc = 0; fc < 4; ++fc) {
      size_t col = bcol + wc * 64 + fc * 16 + cg * 4;
      float4 bv = *(const float4*)&bias[col];
#pragma unroll
      for (int fr = 0; fr < 4; ++fr) {
        size_t r = brow + wr * 64 + fr * 16 + cr;
        float4 o = { acc[fr][fc][0] + bv.x, acc[fr][fc][1] + bv.y,
                     acc[fr][fc][2] + bv.z, acc[fr][fc][3] + bv.w };
        *(float4*)(C + r * N + col) = o;
      }
    }
  } else {
    u16* C = (u16*)Cv;
#pragma unroll
    for (int fc = 0; fc < 4; ++fc) {
      size_t col = bcol + wc * 64 + fc * 16 + cg * 4;
#pragma unroll
      for (int fr = 0; fr < 4; ++fr) {
        size_t r = brow + wr * 64 + fr * 16 + cr;
        uint2 p;
        p.x = (unsigned)f2bf(acc[fr][fc][0]) | ((unsigned)f2bf(acc[fr][fc][1]) << 16);
        p.y = (unsigned)f2bf(acc[fr][fc][2]) | ((unsigned)f2bf(acc[fr][fc][3]) << 16);
        *(uint2*)(C + r * N + col) = p;
      }
    }
  }
}

// ---------------- windowed attention v2 (round-9) + T5 setprio around MFMA clusters ----------------
__global__ __launch_bounds__(256, 3) void attn_kernel(const u16* __restrict__ qkv,
                                                      const float* __restrict__ table,
                                                      u16* __restrict__ aout) {
  __shared__ __align__(16) u16 VT[4][32 * 72];
  const int l = threadIdx.x & 63;
  const int wv = threadIdx.x >> 6;
  const int pair = blockIdx.x * 4 + wv;
  const int head = pair & 15;
  const int win = pair >> 4;
  const int base = ((win >> 6) << 12) + (((win >> 3) & 7) << 9) + ((win & 7) << 3);
  const int cr = l & 15, cg = l >> 4;
  u16* vt = VT[wv];

  {
    const size_t row = base + ((l >> 3) << 6) + (l & 7);
    const u16* vp = qkv + row * 1536 + 1024 + head * 32;
    short8 v0 = *(const short8*)(vp);
    short8 v1 = *(const short8*)(vp + 8);
    short8 v2 = *(const short8*)(vp + 16);
    short8 v3 = *(const short8*)(vp + 24);
#pragma unroll
    for (int j = 0; j < 8; ++j) {
      vt[j * 72 + l] = (u16)v0[j];
      vt[(8 + j) * 72 + l] = (u16)v1[j];
      vt[(16 + j) * 72 + l] = (u16)v2[j];
      vt[(24 + j) * 72 + l] = (u16)v3[j];
    }
  }

  short8 qf[4], kf[4];
#pragma unroll
  for (int i = 0; i < 4; ++i) {
    int t = i * 16 + cr;
    size_t row = base + ((t >> 3) << 6) + (t & 7);
    qf[i] = *(const short8*)(qkv + row * 1536 + head * 32 + cg * 8);
    kf[i] = *(const short8*)(qkv + row * 1536 + 512 + head * 32 + cg * 8);
  }

  const f32x4 zero = {0.f, 0.f, 0.f, 0.f};
  f32x4 s[4][4];
  __builtin_amdgcn_s_setprio(1);
#pragma unroll
  for (int mt = 0; mt < 4; ++mt)
#pragma unroll
    for (int nt = 0; nt < 4; ++nt)
      s[mt][nt] = __builtin_amdgcn_mfma_f32_16x16x32_bf16(kf[mt], qf[nt], zero, 0, 0, 0);
  __builtin_amdgcn_s_setprio(0);

  asm volatile("s_waitcnt lgkmcnt(0)" ::: "memory");
  __builtin_amdgcn_sched_barrier(0);
  short8 vfT[2][2];
#pragma unroll
  for (int dt = 0; dt < 2; ++dt)
#pragma unroll
    for (int kk = 0; kk < 2; ++kk)
      vfT[dt][kk] = *(const short8*)&vt[(dt * 16 + cr) * 72 + kk * 32 + cg * 8];

  const float scale = 0.17677669529663689f;
  f32x4 o[2][4];
#pragma unroll
  for (int dt = 0; dt < 2; ++dt)
#pragma unroll
    for (int nt = 0; nt < 4; ++nt) o[dt][nt] = zero;

  const int laneA = cr + 32 * (cg & 1);
  const int hi = cg >> 1;

#pragma unroll
  for (int nt = 0; nt < 4; ++nt) {
    float p[16];
    float mx = -3.0e38f;
#pragma unroll
    for (int mt = 0; mt < 4; ++mt) {
      float4 tb = *(const float4*)&table[(nt * 16 + cr) * 64 + mt * 16 + cg * 4];
      p[mt * 4 + 0] = s[mt][nt][0] * scale + tb.x;
      p[mt * 4 + 1] = s[mt][nt][1] * scale + tb.y;
      p[mt * 4 + 2] = s[mt][nt][2] * scale + tb.z;
      p[mt * 4 + 3] = s[mt][nt][3] * scale + tb.w;
      mx = fmaxf(mx, fmaxf(fmaxf(p[mt * 4], p[mt * 4 + 1]), fmaxf(p[mt * 4 + 2], p[mt * 4 + 3])));
    }
    mx = fmaxf(mx, __shfl_xor(mx, 16, 64));
    mx = fmaxf(mx, __shfl_xor(mx, 32, 64));
    float sum = 0.f;
#pragma unroll
    for (int i = 0; i < 16; ++i) { p[i] = __expf(p[i] - mx); sum += p[i]; }
    sum += __shfl_xor(sum, 16, 64);
    sum += __shfl_xor(sum, 32, 64);
    const float inv = 1.0f / sum;

    unsigned pk[4][2];
#pragma unroll
    for (int mt = 0; mt < 4; ++mt)
#pragma unroll
      for (int i = 0; i < 2; ++i)
        pk[mt][i] = (unsigned)f2bf(p[mt * 4 + 2 * i] * inv) | ((unsigned)f2bf(p[mt * 4 + 2 * i + 1] * inv) << 16);

#pragma unroll
    for (int kk = 0; kk < 2; ++kk) {
      union { unsigned u[4]; short8 v; } pf;
#pragma unroll
      for (int i = 0; i < 2; ++i) {
        unsigned x0 = (unsigned)__shfl((int)pk[2 * kk][i], laneA, 64);
        unsigned x1 = (unsigned)__shfl((int)pk[2 * kk + 1][i], laneA, 64);
        unsigned y0 = (unsigned)__shfl((int)pk[2 * kk][i], laneA + 16, 64);
        unsigned y1 = (unsigned)__shfl((int)pk[2 * kk + 1][i], laneA + 16, 64);
        pf.u[i] = hi ? x1 : x0;
        pf.u[2 + i] = hi ? y1 : y0;
      }
      __builtin_amdgcn_s_setprio(1);
#pragma unroll
      for (int dt = 0; dt < 2; ++dt)
        o[dt][nt] = __builtin_amdgcn_mfma_f32_16x16x32_bf16(vfT[dt][kk], pf.v, o[dt][nt], 0, 0, 0);
      __builtin_amdgcn_s_setprio(0);
    }
  }

#pragma unroll
  for (int nt = 0; nt < 4; ++nt) {
    int t = nt * 16 + cr;
    size_t row = base + ((t >> 3) << 6) + (t & 7);
#pragma unroll
    for (int dt = 0; dt < 2; ++dt) {
      uint2 pck;
      pck.x = (unsigned)f2bf(o[dt][nt][0]) | ((unsigned)f2bf(o[dt][nt][1]) << 16);
      pck.y = (unsigned)f2bf(o[dt][nt][2]) | ((unsigned)f2bf(o[dt][nt][3]) << 16);
      *(uint2*)(aout + row * 512 + head * 32 + dt * 16 + cg * 4) = pck;
    }
  }
}

// ---------------- launch ----------------
extern "C" void kernel_launch(void* const* d_in, const int* in_sizes, int n_in,
                              void* d_out, int out_size, void* d_ws, size_t ws_size,
                              hipStream_t stream) {
  const float* x = (const float*)d_in[0];
  const float* norm_g = (const float*)d_in[1];
  const float* norm_b = (const float*)d_in[2];
  const float* w_qkv = (const float*)d_in[3];
  const float* w_out = (const float*)d_in[4];
  const float* b_out = (const float*)d_in[5];
  const float* dw0 = (const float*)d_in[6];
  const float* db0 = (const float*)d_in[7];
  const float* dg0 = (const float*)d_in[8];
  const float* dw1 = (const float*)d_in[9];
  const float* db1 = (const float*)d_in[10];
  const float* dg1 = (const float*)d_in[11];
  const float* dw2 = (const float*)d_in[12];
  const float* db2 = (const float*)d_in[13];
  const float* dg2 = (const float*)d_in[14];
  const float* dw3 = (const float*)d_in[15];
  const float* db3 = (const float*)d_in[16];

  char* ws = (char*)d_ws;
  size_t off = 0;
  auto take = [&](size_t bytes) { char* p = ws + off; off += (bytes + 255) & ~(size_t)255; return p; };
  u16* xln = (u16*)take(65536ull * 512 * 2);
  u16* wqkvT = (u16*)take(1536 * 512 * 2);
  u16* woutT = (u16*)take(512 * 512 * 2);
  float* biases = (float*)take(289 * 4);
  float* table = (float*)take(4096 * 4);

  ln_cast_kernel<<<16384, 256, 0, stream>>>(x, norm_g, norm_b, xln);
  prep_w_kernel<<<4096, 256, 0, stream>>>(w_qkv, w_out, wqkvT, woutT);
  dpb_mlp_kernel<<<289, 128, 0, stream>>>(dw0, db0, dg0, dw1, db1, dg1, dw2, db2, dg2, dw3, db3, biases);
  dpb_table_kernel<<<16, 256, 0, stream>>>(biases, table);

  size_t rem = (ws_size > off) ? ws_size - off : 0;
  if (rem >= 32768ull * 1536 * 2 + 65536ull * 512 * 2 + 512) {
    // Round-14 dataflow: {qkv c0, attn c0, qkv c1, attn c1, out-FULL}.
    //  - qkv/attn chunked x2 (round-12 verified: L3-warm producer->consumer, qkvbuf reused)
    //  - out as ONE 2048-block dispatch (2 CU-rounds amortize the 1-round tail;
    //    attnbuf 67MB total stays L3-resident)
    u16* qkvbuf = (u16*)take(32768ull * 1536 * 2);   // reused per chunk
    u16* attnbuf = (u16*)take(65536ull * 512 * 2);   // full (out reads both halves)
    for (int c = 0; c < 2; ++c) {
      const u16* Ac = xln + (size_t)c * 32768 * 512;
      gemm_bk64_kernel<12, false><<<(32768 / 128) * 12, 256, 0, stream>>>(Ac, wqkvT, (void*)qkvbuf, nullptr);
      u16* ac = attnbuf + (size_t)c * 32768 * 512;
      attn_kernel<<<(32768 / 64) * 16 / 4, 256, 0, stream>>>(qkvbuf, table, ac);
    }
    gemm_bk64_kernel<4, true><<<(65536 / 128) * 4, 256, 0, stream>>>(attnbuf, woutT, (void*)d_out, b_out);
  } else {
    // fallback: fully chunked (round-12 path)
    int nch = 4;
    if (rem >= 32768ull * 2048 * 2 + 512) nch = 2;
    const int rows = 65536 / nch;
    u16* qkvbuf = (u16*)take((size_t)rows * 1536 * 2);
    u16* attnbuf = (u16*)take((size_t)rows * 512 * 2);
    for (int c = 0; c < nch; ++c) {
      const u16* Ac = xln + (size_t)c * rows * 512;
      gemm_bk64_kernel<12, false><<<(rows / 128) * 12, 256, 0, stream>>>(Ac, wqkvT, (void*)qkvbuf, nullptr);
      attn_kernel<<<(rows / 64) * 16 / 4, 256, 0, stream>>>(qkvbuf, table, attnbuf);
      float* Cc = (float*)d_out + (size_t)c * rows * 512;
      gemm_bk64_kernel<4, true><<<(rows / 128) * 4, 256, 0, stream>>>(attnbuf, woutT, (void*)Cc, b_out);
    }
  }
}

// Round 15
// 339.523 us; speedup vs baseline: 1.0527x; 1.0066x over previous
//
#include <hip/hip_runtime.h>
#include <cstdint>
#include <cstddef>

typedef unsigned short u16;
typedef __attribute__((ext_vector_type(8))) short short8;
typedef __attribute__((ext_vector_type(4))) float f32x4;
typedef __attribute__((ext_vector_type(4))) unsigned short us4;

#define AS1 __attribute__((address_space(1)))
#define AS3 __attribute__((address_space(3)))

__device__ __forceinline__ u16 f2bf(float f) {
  union { float f; unsigned u; } v; v.f = f;
  unsigned r = v.u + 0x7fffu + ((v.u >> 16) & 1u);
  return (u16)(r >> 16);
}

__device__ __forceinline__ void gload_lds16(const u16* g, u16* l) {
  __builtin_amdgcn_global_load_lds((AS1 void*)g, (AS3 void*)l, 16, 0, 0);
}

// ---------------- LayerNorm + cast to bf16 (token-major) ----------------
__global__ void ln_cast_kernel(const float* __restrict__ x, const float* __restrict__ g,
                               const float* __restrict__ b, u16* __restrict__ out) {
  const int lane = threadIdx.x & 63;
  const int tok = blockIdx.x * 4 + (threadIdx.x >> 6);
  const float4* row = (const float4*)(x + (size_t)tok * 512);
  float4 v0 = row[lane];
  float4 v1 = row[lane + 64];
  float s = v0.x + v0.y + v0.z + v0.w + v1.x + v1.y + v1.z + v1.w;
  float q = v0.x*v0.x + v0.y*v0.y + v0.z*v0.z + v0.w*v0.w
          + v1.x*v1.x + v1.y*v1.y + v1.z*v1.z + v1.w*v1.w;
#pragma unroll
  for (int m = 1; m < 64; m <<= 1) { s += __shfl_xor(s, m, 64); q += __shfl_xor(q, m, 64); }
  const float mean = s * (1.0f / 512.0f);
  const float var = q * (1.0f / 512.0f) - mean * mean;
  const float r = rsqrtf(var + 1e-5f);
  const float4* g4 = (const float4*)g;
  const float4* b4 = (const float4*)b;
  float4 ga = g4[lane], gb = g4[lane + 64];
  float4 ba = b4[lane], bb = b4[lane + 64];
  us4 o0 = { f2bf((v0.x - mean) * r * ga.x + ba.x), f2bf((v0.y - mean) * r * ga.y + ba.y),
             f2bf((v0.z - mean) * r * ga.z + ba.z), f2bf((v0.w - mean) * r * ga.w + ba.w) };
  us4 o1 = { f2bf((v1.x - mean) * r * gb.x + bb.x), f2bf((v1.y - mean) * r * gb.y + bb.y),
             f2bf((v1.z - mean) * r * gb.z + bb.z), f2bf((v1.w - mean) * r * gb.w + bb.w) };
  *(us4*)(out + (size_t)tok * 512 + lane * 4) = o0;
  *(us4*)(out + (size_t)tok * 512 + 256 + lane * 4) = o1;
}

// ---------------- weight transpose + cast ----------------
__global__ void prep_w_kernel(const float* __restrict__ wqkv, const float* __restrict__ wout,
                              u16* __restrict__ wqkvT, u16* __restrict__ woutT) {
  int idx = blockIdx.x * blockDim.x + threadIdx.x;
  if (idx < 512 * 1536) {
    int n = idx >> 9, k = idx & 511;
    wqkvT[idx] = f2bf(wqkv[k * 1536 + n]);
  } else {
    int j = idx - 512 * 1536;
    if (j < 512 * 512) {
      int n = j >> 9, k = j & 511;
      woutT[j] = f2bf(wout[k * 512 + n]);
    }
  }
}

// ---------------- DPB MLP ----------------
__device__ __forceinline__ float lnrelu128(float a, float g, float* red, int tid) {
  float s = a, q = a * a;
#pragma unroll
  for (int m = 1; m < 64; m <<= 1) { s += __shfl_xor(s, m, 64); q += __shfl_xor(q, m, 64); }
  __syncthreads();
  if ((tid & 63) == 0) { red[tid >> 6] = s; red[2 + (tid >> 6)] = q; }
  __syncthreads();
  float S = red[0] + red[1], Q = red[2] + red[3];
  float mean = S * (1.f / 128.f);
  float var = Q * (1.f / 128.f) - mean * mean;
  float y = (a - mean) * rsqrtf(var + 1e-5f) * g;
  return fmaxf(y, 0.f);
}

__global__ void dpb_mlp_kernel(const float* __restrict__ w0, const float* __restrict__ b0, const float* __restrict__ g0,
                               const float* __restrict__ w1, const float* __restrict__ b1, const float* __restrict__ g1,
                               const float* __restrict__ w2, const float* __restrict__ b2, const float* __restrict__ g2,
                               const float* __restrict__ w3, const float* __restrict__ b3,
                               float* __restrict__ biases) {
  __shared__ float h[128];
  __shared__ float red[4];
  const int tid = threadIdx.x;
  const int row = blockIdx.x;
  const float p0 = (float)(row / 17) - 8.0f;
  const float p1 = (float)(row % 17) - 8.0f;
  float a = p0 * w0[tid] + p1 * w0[128 + tid] + b0[tid];
  a = lnrelu128(a, g0[tid], red, tid);
  h[tid] = a;
  __syncthreads();
  float acc = b1[tid];
  for (int i = 0; i < 128; ++i) acc += h[i] * w1[i * 128 + tid];
  acc = lnrelu128(acc, g1[tid], red, tid);
  h[tid] = acc;
  __syncthreads();
  float acc2 = b2[tid];
  for (int i = 0; i < 128; ++i) acc2 += h[i] * w2[i * 128 + tid];
  acc2 = lnrelu128(acc2, g2[tid], red, tid);
  float t = acc2 * w3[tid];
#pragma unroll
  for (int m = 1; m < 64; m <<= 1) t += __shfl_xor(t, m, 64);
  __syncthreads();
  if ((tid & 63) == 0) red[tid >> 6] = t;
  __syncthreads();
  if (tid == 0) biases[row] = red[0] + red[1] + b3[0];
}

__global__ void dpb_table_kernel(const float* __restrict__ biases, float* __restrict__ table) {
  int t = blockIdx.x * blockDim.x + threadIdx.x;
  if (t < 4096) {
    int i = t >> 6, j = t & 63;
    int r0 = (i >> 3) - (j >> 3) + 7;
    int r1 = (i & 7) - (j & 7) + 7;
    table[t] = biases[r0 * 15 + r1];
  }
}

// ---------------- 128x128 bf16 GEMM, BK=64, 4 blocks/CU (round-10, verified) ----------------
template <int CT, bool F32OUT>
__global__ __launch_bounds__(256, 4) void gemm_bk64_kernel(const u16* __restrict__ A, const u16* __restrict__ BT,
                                                           void* __restrict__ Cv, const float* __restrict__ bias) {
  __shared__ __align__(16) u16 As[128 * 64];
  __shared__ __align__(16) u16 Bs[128 * 64];
  const int tid = threadIdx.x;
  const int w = tid >> 6, l = tid & 63;
  const int wr = w >> 1, wc = w & 1;
  const int cr = l & 15, cg = l >> 4;
  const int hcr = (cr + ((cr >> 3) << 2)) & 7;   // read-side swizzle (lane-constant)

  const int hw = blockIdx.x;
  const int ix = hw >> 3;
  const int rt = (hw & 7) + 8 * (ix / CT);
  const int ct = ix % CT;
  const size_t brow = (size_t)rt * 128;
  const size_t bcol = (size_t)ct * 128;
  const int N = CT * 128;

  const int srow8 = tid >> 3;
  const int hsrc = ((srow8 & 15) + (((srow8 >> 3) & 1) << 2)) & 7;
  const int csrc = ((tid & 7) ^ hsrc) * 8;
  const u16* gA = A + (brow + srow8) * 512 + csrc;
  const u16* gB = BT + (bcol + srow8) * 512 + csrc;

  const f32x4 zero = {0.f, 0.f, 0.f, 0.f};
  f32x4 acc[4][4];
#pragma unroll
  for (int i = 0; i < 4; ++i)
#pragma unroll
    for (int j = 0; j < 4; ++j) acc[i][j] = zero;

  const u16* aP = &As[(wr * 64 + cr) * 64];
  const u16* bP = &Bs[(wc * 64 + cr) * 64];

  for (int k0 = 0; k0 < 512; k0 += 64) {
#pragma unroll
    for (int j = 0; j < 4; ++j) {
      gload_lds16(gA + (size_t)j * 32 * 512 + k0, &As[j * 2048 + w * 512]);
      gload_lds16(gB + (size_t)j * 32 * 512 + k0, &Bs[j * 2048 + w * 512]);
    }
    __syncthreads();
#pragma unroll
    for (int ks = 0; ks < 2; ++ks) {
      short8 af[4], bf[4];
      const int pco = ((ks * 4 + cg) ^ hcr) * 8;
#pragma unroll
      for (int fr = 0; fr < 4; ++fr) af[fr] = *(const short8*)(aP + fr * 1024 + pco);
#pragma unroll
      for (int fc = 0; fc < 4; ++fc) bf[fc] = *(const short8*)(bP + fc * 1024 + pco);
#pragma unroll
      for (int fr = 0; fr < 4; ++fr)
#pragma unroll
        for (int fc = 0; fc < 4; ++fc)
          acc[fr][fc] = __builtin_amdgcn_mfma_f32_16x16x32_bf16(bf[fc], af[fr], acc[fr][fc], 0, 0, 0);
    }
    __syncthreads();
  }

  if (F32OUT) {
    float* C = (float*)Cv;
#pragma unroll
    for (int fc = 0; fc < 4; ++fc) {
      size_t col = bcol + wc * 64 + fc * 16 + cg * 4;
      float4 bv = *(const float4*)&bias[col];
#pragma unroll
      for (int fr = 0; fr < 4; ++fr) {
        size_t r = brow + wr * 64 + fr * 16 + cr;
        float4 o = { acc[fr][fc][0] + bv.x, acc[fr][fc][1] + bv.y,
                     acc[fr][fc][2] + bv.z, acc[fr][fc][3] + bv.w };
        *(float4*)(C + r * N + col) = o;
      }
    }
  } else {
    u16* C = (u16*)Cv;
#pragma unroll
    for (int fc = 0; fc < 4; ++fc) {
      size_t col = bcol + wc * 64 + fc * 16 + cg * 4;
#pragma unroll
      for (int fr = 0; fr < 4; ++fr) {
        size_t r = brow + wr * 64 + fr * 16 + cr;
        uint2 p;
        p.x = (unsigned)f2bf(acc[fr][fc][0]) | ((unsigned)f2bf(acc[fr][fc][1]) << 16);
        p.y = (unsigned)f2bf(acc[fr][fc][2]) | ((unsigned)f2bf(acc[fr][fc][3]) << 16);
        *(uint2*)(C + r * N + col) = p;
      }
    }
  }
}

// ---------------- windowed attention v3: coalesced V load + LDS transpose ----------------
// v2's V load was a 64-line gather per instruction (lane=token, 3KB stride). v3 loads V
// with the same 16-line fragment pattern as Q/K (lane (cr,cg): token mt*16+cr, d=cg*8..+7)
// and transposes via LDS. VT stride 74 u16: write-side cg-groups land on distinct bank
// quads (8*74*2/4 mod 32 = 8), read-side <=2-way. Table prefetched to registers.
__global__ __launch_bounds__(256, 3) void attn_kernel(const u16* __restrict__ qkv,
                                                      const float* __restrict__ table,
                                                      u16* __restrict__ aout) {
  __shared__ __align__(16) u16 VT[4][32 * 74];
  const int l = threadIdx.x & 63;
  const int wv = threadIdx.x >> 6;
  const int pair = blockIdx.x * 4 + wv;
  const int head = pair & 15;
  const int win = pair >> 4;
  const int base = ((win >> 6) << 12) + (((win >> 3) & 7) << 9) + ((win & 7) << 3);
  const int cr = l & 15, cg = l >> 4;
  u16* vt = VT[wv];

  // all global loads issue first (q, k, v fragments: 16-line pattern each)
  short8 qf[4], kf[4], vl[4];
#pragma unroll
  for (int i = 0; i < 4; ++i) {
    int t = i * 16 + cr;
    size_t row = base + ((t >> 3) << 6) + (t & 7);
    const u16* rp = qkv + row * 1536 + head * 32 + cg * 8;
    qf[i] = *(const short8*)(rp);
    kf[i] = *(const short8*)(rp + 512);
    vl[i] = *(const short8*)(rp + 1024);
  }
  // table prefetch: tb[nt] = bias row (q = nt*16+cr), cols mt-block cg*4..cg*4+3 per mt
  float4 tb[4][1];
  // (loaded inside softmax loop previously; prefetch all 16 floats = 4 float4 per lane)
  float4 tbl[4];
#pragma unroll
  for (int nt = 0; nt < 4; ++nt) tbl[nt] = *(const float4*)&table[(nt * 16 + cr) * 64 + 0 * 16 + cg * 4];
  // note: tbl[nt] covers mt=0 only; mt 1..3 rows loaded below (kept: table is L1-hot, 16B strided)

  // V transpose into LDS: VT[d][token], d = cg*8+j, token = mt*16+cr
#pragma unroll
  for (int mt = 0; mt < 4; ++mt)
#pragma unroll
    for (int j = 0; j < 8; ++j)
      vt[(cg * 8 + j) * 74 + mt * 16 + cr] = (u16)vl[mt][j];

  const f32x4 zero = {0.f, 0.f, 0.f, 0.f};
  f32x4 s[4][4];
  __builtin_amdgcn_s_setprio(1);
#pragma unroll
  for (int mt = 0; mt < 4; ++mt)
#pragma unroll
    for (int nt = 0; nt < 4; ++nt)
      s[mt][nt] = __builtin_amdgcn_mfma_f32_16x16x32_bf16(kf[mt], qf[nt], zero, 0, 0, 0);
  __builtin_amdgcn_s_setprio(0);

  // per-wave fence: VT writes -> vfT reads (wave-private LDS arena, no barrier)
  asm volatile("s_waitcnt lgkmcnt(0)" ::: "memory");
  __builtin_amdgcn_sched_barrier(0);
  short8 vfT[2][2];  // [dt][kk]: operand row = d = dt*16+cr, k = token kk*32+cg*8+j
#pragma unroll
  for (int dt = 0; dt < 2; ++dt)
#pragma unroll
    for (int kk = 0; kk < 2; ++kk)
      vfT[dt][kk] = *(const short8*)&vt[(dt * 16 + cr) * 74 + kk * 32 + cg * 8];

  const float scale = 0.17677669529663689f;
  f32x4 o[2][4];
#pragma unroll
  for (int dt = 0; dt < 2; ++dt)
#pragma unroll
    for (int nt = 0; nt < 4; ++nt) o[dt][nt] = zero;

  const int laneA = cr + 32 * (cg & 1);
  const int hi = cg >> 1;

#pragma unroll
  for (int nt = 0; nt < 4; ++nt) {
    float p[16];
    float mx = -3.0e38f;
#pragma unroll
    for (int mt = 0; mt < 4; ++mt) {
      float4 tbv = (mt == 0) ? tbl[nt] : *(const float4*)&table[(nt * 16 + cr) * 64 + mt * 16 + cg * 4];
      p[mt * 4 + 0] = s[mt][nt][0] * scale + tbv.x;
      p[mt * 4 + 1] = s[mt][nt][1] * scale + tbv.y;
      p[mt * 4 + 2] = s[mt][nt][2] * scale + tbv.z;
      p[mt * 4 + 3] = s[mt][nt][3] * scale + tbv.w;
      mx = fmaxf(mx, fmaxf(fmaxf(p[mt * 4], p[mt * 4 + 1]), fmaxf(p[mt * 4 + 2], p[mt * 4 + 3])));
    }
    mx = fmaxf(mx, __shfl_xor(mx, 16, 64));
    mx = fmaxf(mx, __shfl_xor(mx, 32, 64));
    float sum = 0.f;
#pragma unroll
    for (int i = 0; i < 16; ++i) { p[i] = __expf(p[i] - mx); sum += p[i]; }
    sum += __shfl_xor(sum, 16, 64);
    sum += __shfl_xor(sum, 32, 64);
    const float inv = 1.0f / sum;

    unsigned pk[4][2];
#pragma unroll
    for (int mt = 0; mt < 4; ++mt)
#pragma unroll
      for (int i = 0; i < 2; ++i)
        pk[mt][i] = (unsigned)f2bf(p[mt * 4 + 2 * i] * inv) | ((unsigned)f2bf(p[mt * 4 + 2 * i + 1] * inv) << 16);

#pragma unroll
    for (int kk = 0; kk < 2; ++kk) {
      union { unsigned u[4]; short8 v; } pf;
#pragma unroll
      for (int i = 0; i < 2; ++i) {
        unsigned x0 = (unsigned)__shfl((int)pk[2 * kk][i], laneA, 64);
        unsigned x1 = (unsigned)__shfl((int)pk[2 * kk + 1][i], laneA, 64);
        unsigned y0 = (unsigned)__shfl((int)pk[2 * kk][i], laneA + 16, 64);
        unsigned y1 = (unsigned)__shfl((int)pk[2 * kk + 1][i], laneA + 16, 64);
        pf.u[i] = hi ? x1 : x0;
        pf.u[2 + i] = hi ? y1 : y0;
      }
      __builtin_amdgcn_s_setprio(1);
#pragma unroll
      for (int dt = 0; dt < 2; ++dt)
        o[dt][nt] = __builtin_amdgcn_mfma_f32_16x16x32_bf16(vfT[dt][kk], pf.v, o[dt][nt], 0, 0, 0);
      __builtin_amdgcn_s_setprio(0);
    }
  }

#pragma unroll
  for (int nt = 0; nt < 4; ++nt) {
    int t = nt * 16 + cr;
    size_t row = base + ((t >> 3) << 6) + (t & 7);
#pragma unroll
    for (int dt = 0; dt < 2; ++dt) {
      uint2 pck;
      pck.x = (unsigned)f2bf(o[dt][nt][0]) | ((unsigned)f2bf(o[dt][nt][1]) << 16);
      pck.y = (unsigned)f2bf(o[dt][nt][2]) | ((unsigned)f2bf(o[dt][nt][3]) << 16);
      *(uint2*)(aout + row * 512 + head * 32 + dt * 16 + cg * 4) = pck;
    }
  }
}

// ---------------- launch (round-12 dataflow: nch=2 full pipeline, verified 340.9) ----------------
extern "C" void kernel_launch(void* const* d_in, const int* in_sizes, int n_in,
                              void* d_out, int out_size, void* d_ws, size_t ws_size,
                              hipStream_t stream) {
  const float* x = (const float*)d_in[0];
  const float* norm_g = (const float*)d_in[1];
  const float* norm_b = (const float*)d_in[2];
  const float* w_qkv = (const float*)d_in[3];
  const float* w_out = (const float*)d_in[4];
  const float* b_out = (const float*)d_in[5];
  const float* dw0 = (const float*)d_in[6];
  const float* db0 = (const float*)d_in[7];
  const float* dg0 = (const float*)d_in[8];
  const float* dw1 = (const float*)d_in[9];
  const float* db1 = (const float*)d_in[10];
  const float* dg1 = (const float*)d_in[11];
  const float* dw2 = (const float*)d_in[12];
  const float* db2 = (const float*)d_in[13];
  const float* dg2 = (const float*)d_in[14];
  const float* dw3 = (const float*)d_in[15];
  const float* db3 = (const float*)d_in[16];

  char* ws = (char*)d_ws;
  size_t off = 0;
  auto take = [&](size_t bytes) { char* p = ws + off; off += (bytes + 255) & ~(size_t)255; return p; };
  u16* xln = (u16*)take(65536ull * 512 * 2);
  u16* wqkvT = (u16*)take(1536 * 512 * 2);
  u16* woutT = (u16*)take(512 * 512 * 2);
  float* biases = (float*)take(289 * 4);
  float* table = (float*)take(4096 * 4);

  ln_cast_kernel<<<16384, 256, 0, stream>>>(x, norm_g, norm_b, xln);
  prep_w_kernel<<<4096, 256, 0, stream>>>(w_qkv, w_out, wqkvT, woutT);
  dpb_mlp_kernel<<<289, 128, 0, stream>>>(dw0, db0, dg0, dw1, db1, dg1, dw2, db2, dg2, dw3, db3, biases);
  dpb_table_kernel<<<16, 256, 0, stream>>>(biases, table);

  size_t rem = (ws_size > off) ? ws_size - off : 0;
  int nch = 4;
  if (rem >= 32768ull * 2048 * 2 + 512) nch = 2;
  const int rows = 65536 / nch;
  u16* qkvbuf = (u16*)take((size_t)rows * 1536 * 2);
  u16* attnbuf = (u16*)take((size_t)rows * 512 * 2);

  for (int c = 0; c < nch; ++c) {
    const u16* Ac = xln + (size_t)c * rows * 512;
    gemm_bk64_kernel<12, false><<<(rows / 128) * 12, 256, 0, stream>>>(Ac, wqkvT, (void*)qkvbuf, nullptr);
    attn_kernel<<<(rows / 64) * 16 / 4, 256, 0, stream>>>(qkvbuf, table, attnbuf);
    float* Cc = (float*)d_out + (size_t)c * rows * 512;
    gemm_bk64_kernel<4, true><<<(rows / 128) * 4, 256, 0, stream>>>(attnbuf, woutT, (void*)Cc, b_out);
  }
}

// Round 16
// 335.017 us; speedup vs baseline: 1.0668x; 1.0134x over previous
//
#include <hip/hip_runtime.h>
#include <cstdint>
#include <cstddef>

typedef unsigned short u16;
typedef __attribute__((ext_vector_type(8))) short short8;
typedef __attribute__((ext_vector_type(4))) float f32x4;
typedef __attribute__((ext_vector_type(4))) unsigned short us4;

#define AS1 __attribute__((address_space(1)))
#define AS3 __attribute__((address_space(3)))

__device__ __forceinline__ u16 f2bf(float f) {
  union { float f; unsigned u; } v; v.f = f;
  unsigned r = v.u + 0x7fffu + ((v.u >> 16) & 1u);
  return (u16)(r >> 16);
}

__device__ __forceinline__ void gload_lds16(const u16* g, u16* l) {
  __builtin_amdgcn_global_load_lds((AS1 void*)g, (AS3 void*)l, 16, 0, 0);
}

// ---------------- LayerNorm + cast to bf16 (token-major) ----------------
__global__ void ln_cast_kernel(const float* __restrict__ x, const float* __restrict__ g,
                               const float* __restrict__ b, u16* __restrict__ out) {
  const int lane = threadIdx.x & 63;
  const int tok = blockIdx.x * 4 + (threadIdx.x >> 6);
  const float4* row = (const float4*)(x + (size_t)tok * 512);
  float4 v0 = row[lane];
  float4 v1 = row[lane + 64];
  float s = v0.x + v0.y + v0.z + v0.w + v1.x + v1.y + v1.z + v1.w;
  float q = v0.x*v0.x + v0.y*v0.y + v0.z*v0.z + v0.w*v0.w
          + v1.x*v1.x + v1.y*v1.y + v1.z*v1.z + v1.w*v1.w;
#pragma unroll
  for (int m = 1; m < 64; m <<= 1) { s += __shfl_xor(s, m, 64); q += __shfl_xor(q, m, 64); }
  const float mean = s * (1.0f / 512.0f);
  const float var = q * (1.0f / 512.0f) - mean * mean;
  const float r = rsqrtf(var + 1e-5f);
  const float4* g4 = (const float4*)g;
  const float4* b4 = (const float4*)b;
  float4 ga = g4[lane], gb = g4[lane + 64];
  float4 ba = b4[lane], bb = b4[lane + 64];
  us4 o0 = { f2bf((v0.x - mean) * r * ga.x + ba.x), f2bf((v0.y - mean) * r * ga.y + ba.y),
             f2bf((v0.z - mean) * r * ga.z + ba.z), f2bf((v0.w - mean) * r * ga.w + ba.w) };
  us4 o1 = { f2bf((v1.x - mean) * r * gb.x + bb.x), f2bf((v1.y - mean) * r * gb.y + bb.y),
             f2bf((v1.z - mean) * r * gb.z + bb.z), f2bf((v1.w - mean) * r * gb.w + bb.w) };
  *(us4*)(out + (size_t)tok * 512 + lane * 4) = o0;
  *(us4*)(out + (size_t)tok * 512 + 256 + lane * 4) = o1;
}

// ---------------- weight transpose + cast ----------------
__global__ void prep_w_kernel(const float* __restrict__ wqkv, const float* __restrict__ wout,
                              u16* __restrict__ wqkvT, u16* __restrict__ woutT) {
  int idx = blockIdx.x * blockDim.x + threadIdx.x;
  if (idx < 512 * 1536) {
    int n = idx >> 9, k = idx & 511;
    wqkvT[idx] = f2bf(wqkv[k * 1536 + n]);
  } else {
    int j = idx - 512 * 1536;
    if (j < 512 * 512) {
      int n = j >> 9, k = j & 511;
      woutT[j] = f2bf(wout[k * 512 + n]);
    }
  }
}

// ---------------- DPB MLP ----------------
__device__ __forceinline__ float lnrelu128(float a, float g, float* red, int tid) {
  float s = a, q = a * a;
#pragma unroll
  for (int m = 1; m < 64; m <<= 1) { s += __shfl_xor(s, m, 64); q += __shfl_xor(q, m, 64); }
  __syncthreads();
  if ((tid & 63) == 0) { red[tid >> 6] = s; red[2 + (tid >> 6)] = q; }
  __syncthreads();
  float S = red[0] + red[1], Q = red[2] + red[3];
  float mean = S * (1.f / 128.f);
  float var = Q * (1.f / 128.f) - mean * mean;
  float y = (a - mean) * rsqrtf(var + 1e-5f) * g;
  return fmaxf(y, 0.f);
}

__global__ void dpb_mlp_kernel(const float* __restrict__ w0, const float* __restrict__ b0, const float* __restrict__ g0,
                               const float* __restrict__ w1, const float* __restrict__ b1, const float* __restrict__ g1,
                               const float* __restrict__ w2, const float* __restrict__ b2, const float* __restrict__ g2,
                               const float* __restrict__ w3, const float* __restrict__ b3,
                               float* __restrict__ biases) {
  __shared__ float h[128];
  __shared__ float red[4];
  const int tid = threadIdx.x;
  const int row = blockIdx.x;
  const float p0 = (float)(row / 17) - 8.0f;
  const float p1 = (float)(row % 17) - 8.0f;
  float a = p0 * w0[tid] + p1 * w0[128 + tid] + b0[tid];
  a = lnrelu128(a, g0[tid], red, tid);
  h[tid] = a;
  __syncthreads();
  float acc = b1[tid];
  for (int i = 0; i < 128; ++i) acc += h[i] * w1[i * 128 + tid];
  acc = lnrelu128(acc, g1[tid], red, tid);
  h[tid] = acc;
  __syncthreads();
  float acc2 = b2[tid];
  for (int i = 0; i < 128; ++i) acc2 += h[i] * w2[i * 128 + tid];
  acc2 = lnrelu128(acc2, g2[tid], red, tid);
  float t = acc2 * w3[tid];
#pragma unroll
  for (int m = 1; m < 64; m <<= 1) t += __shfl_xor(t, m, 64);
  __syncthreads();
  if ((tid & 63) == 0) red[tid >> 6] = t;
  __syncthreads();
  if (tid == 0) biases[row] = red[0] + red[1] + b3[0];
}

__global__ void dpb_table_kernel(const float* __restrict__ biases, float* __restrict__ table) {
  int t = blockIdx.x * blockDim.x + threadIdx.x;
  if (t < 4096) {
    int i = t >> 6, j = t & 63;
    int r0 = (i >> 3) - (j >> 3) + 7;
    int r1 = (i & 7) - (j & 7) + 7;
    table[t] = biases[r0 * 15 + r1];
  }
}

// ---------------- 128x128 bf16 GEMM, BK=64, 4 blocks/CU (round-10, verified) ----------------
template <int CT, bool F32OUT>
__global__ __launch_bounds__(256, 4) void gemm_bk64_kernel(const u16* __restrict__ A, const u16* __restrict__ BT,
                                                           void* __restrict__ Cv, const float* __restrict__ bias) {
  __shared__ __align__(16) u16 As[128 * 64];
  __shared__ __align__(16) u16 Bs[128 * 64];
  const int tid = threadIdx.x;
  const int w = tid >> 6, l = tid & 63;
  const int wr = w >> 1, wc = w & 1;
  const int cr = l & 15, cg = l >> 4;
  const int hcr = (cr + ((cr >> 3) << 2)) & 7;

  const int hw = blockIdx.x;
  const int ix = hw >> 3;
  const int rt = (hw & 7) + 8 * (ix / CT);
  const int ct = ix % CT;
  const size_t brow = (size_t)rt * 128;
  const size_t bcol = (size_t)ct * 128;
  const int N = CT * 128;

  const int srow8 = tid >> 3;
  const int hsrc = ((srow8 & 15) + (((srow8 >> 3) & 1) << 2)) & 7;
  const int csrc = ((tid & 7) ^ hsrc) * 8;
  const u16* gA = A + (brow + srow8) * 512 + csrc;
  const u16* gB = BT + (bcol + srow8) * 512 + csrc;

  const f32x4 zero = {0.f, 0.f, 0.f, 0.f};
  f32x4 acc[4][4];
#pragma unroll
  for (int i = 0; i < 4; ++i)
#pragma unroll
    for (int j = 0; j < 4; ++j) acc[i][j] = zero;

  const u16* aP = &As[(wr * 64 + cr) * 64];
  const u16* bP = &Bs[(wc * 64 + cr) * 64];

  for (int k0 = 0; k0 < 512; k0 += 64) {
#pragma unroll
    for (int j = 0; j < 4; ++j) {
      gload_lds16(gA + (size_t)j * 32 * 512 + k0, &As[j * 2048 + w * 512]);
      gload_lds16(gB + (size_t)j * 32 * 512 + k0, &Bs[j * 2048 + w * 512]);
    }
    __syncthreads();
#pragma unroll
    for (int ks = 0; ks < 2; ++ks) {
      short8 af[4], bf[4];
      const int pco = ((ks * 4 + cg) ^ hcr) * 8;
#pragma unroll
      for (int fr = 0; fr < 4; ++fr) af[fr] = *(const short8*)(aP + fr * 1024 + pco);
#pragma unroll
      for (int fc = 0; fc < 4; ++fc) bf[fc] = *(const short8*)(bP + fc * 1024 + pco);
#pragma unroll
      for (int fr = 0; fr < 4; ++fr)
#pragma unroll
        for (int fc = 0; fc < 4; ++fc)
          acc[fr][fc] = __builtin_amdgcn_mfma_f32_16x16x32_bf16(bf[fc], af[fr], acc[fr][fc], 0, 0, 0);
    }
    __syncthreads();
  }

  if (F32OUT) {
    float* C = (float*)Cv;
#pragma unroll
    for (int fc = 0; fc < 4; ++fc) {
      size_t col = bcol + wc * 64 + fc * 16 + cg * 4;
      float4 bv = *(const float4*)&bias[col];
#pragma unroll
      for (int fr = 0; fr < 4; ++fr) {
        size_t r = brow + wr * 64 + fr * 16 + cr;
        float4 o = { acc[fr][fc][0] + bv.x, acc[fr][fc][1] + bv.y,
                     acc[fr][fc][2] + bv.z, acc[fr][fc][3] + bv.w };
        *(float4*)(C + r * N + col) = o;
      }
    }
  } else {
    u16* C = (u16*)Cv;
#pragma unroll
    for (int fc = 0; fc < 4; ++fc) {
      size_t col = bcol + wc * 64 + fc * 16 + cg * 4;
#pragma unroll
      for (int fr = 0; fr < 4; ++fr) {
        size_t r = brow + wr * 64 + fr * 16 + cr;
        uint2 p;
        p.x = (unsigned)f2bf(acc[fr][fc][0]) | ((unsigned)f2bf(acc[fr][fc][1]) << 16);
        p.y = (unsigned)f2bf(acc[fr][fc][2]) | ((unsigned)f2bf(acc[fr][fc][3]) << 16);
        *(uint2*)(C + r * N + col) = p;
      }
    }
  }
}

// ---------------- windowed attention v4: streaming-nt, low register pressure ----------------
// v2/v3 materialized s[4][4] (64 VGPR) + q/k/v (96) at once -> live set ~190 > the
// launch_bounds(256,3) cap (~168 VGPR) -> scratch spills (the invisible 2.5x-over-roofline
// cost that survived every memory-layout fix). v4 streams one nt (16 q-cols) at a time:
// {4 QK^T MFMA -> softmax -> pack/shfl -> 4 PV MFMA -> store}. Peak live ~150 VGPR, no spill.
__global__ __launch_bounds__(256, 3) void attn_kernel(const u16* __restrict__ qkv,
                                                      const float* __restrict__ table,
                                                      u16* __restrict__ aout) {
  __shared__ __align__(16) u16 VT[4][32 * 74];
  const int l = threadIdx.x & 63;
  const int wv = threadIdx.x >> 6;
  const int pair = blockIdx.x * 4 + wv;
  const int head = pair & 15;
  const int win = pair >> 4;
  const int base = ((win >> 6) << 12) + (((win >> 3) & 7) << 9) + ((win & 7) << 3);
  const int cr = l & 15, cg = l >> 4;
  u16* vt = VT[wv];

  // coalesced fragment loads (16-line pattern): q,k kept in regs; v transposed to LDS
  short8 qf[4], kf[4];
  {
    short8 vl[4];
#pragma unroll
    for (int i = 0; i < 4; ++i) {
      int t = i * 16 + cr;
      size_t row = base + ((t >> 3) << 6) + (t & 7);
      const u16* rp = qkv + row * 1536 + head * 32 + cg * 8;
      qf[i] = *(const short8*)(rp);
      kf[i] = *(const short8*)(rp + 512);
      vl[i] = *(const short8*)(rp + 1024);
    }
#pragma unroll
    for (int mt = 0; mt < 4; ++mt)
#pragma unroll
      for (int j = 0; j < 8; ++j)
        vt[(cg * 8 + j) * 74 + mt * 16 + cr] = (u16)vl[mt][j];
  }

  // per-wave fence: VT writes -> vfT reads (wave-private arena, no barrier)
  asm volatile("s_waitcnt lgkmcnt(0)" ::: "memory");
  __builtin_amdgcn_sched_barrier(0);
  short8 vfT[2][2];  // [dt][kk]: operand row = d = dt*16+cr, k = token kk*32+cg*8+j
#pragma unroll
  for (int dt = 0; dt < 2; ++dt)
#pragma unroll
    for (int kk = 0; kk < 2; ++kk)
      vfT[dt][kk] = *(const short8*)&vt[(dt * 16 + cr) * 74 + kk * 32 + cg * 8];

  const f32x4 zero = {0.f, 0.f, 0.f, 0.f};
  const float scale = 0.17677669529663689f;
  const int laneA = cr + 32 * (cg & 1);
  const int hi = cg >> 1;

#pragma unroll
  for (int nt = 0; nt < 4; ++nt) {
    // QK^T for this q-column block: s4[mt], D col = q = nt*16+cr, D row = k = mt*16+cg*4+reg
    f32x4 s4[4];
    __builtin_amdgcn_s_setprio(1);
#pragma unroll
    for (int mt = 0; mt < 4; ++mt)
      s4[mt] = __builtin_amdgcn_mfma_f32_16x16x32_bf16(kf[mt], qf[nt], zero, 0, 0, 0);
    __builtin_amdgcn_s_setprio(0);

    float p[16];
    float mx = -3.0e38f;
#pragma unroll
    for (int mt = 0; mt < 4; ++mt) {
      float4 tb = *(const float4*)&table[(nt * 16 + cr) * 64 + mt * 16 + cg * 4];
      p[mt * 4 + 0] = s4[mt][0] * scale + tb.x;
      p[mt * 4 + 1] = s4[mt][1] * scale + tb.y;
      p[mt * 4 + 2] = s4[mt][2] * scale + tb.z;
      p[mt * 4 + 3] = s4[mt][3] * scale + tb.w;
      mx = fmaxf(mx, fmaxf(fmaxf(p[mt * 4], p[mt * 4 + 1]), fmaxf(p[mt * 4 + 2], p[mt * 4 + 3])));
    }
    mx = fmaxf(mx, __shfl_xor(mx, 16, 64));
    mx = fmaxf(mx, __shfl_xor(mx, 32, 64));
    float sum = 0.f;
#pragma unroll
    for (int i = 0; i < 16; ++i) { p[i] = __expf(p[i] - mx); sum += p[i]; }
    sum += __shfl_xor(sum, 16, 64);
    sum += __shfl_xor(sum, 32, 64);
    const float inv = 1.0f / sum;

    unsigned pk[4][2];
#pragma unroll
    for (int mt = 0; mt < 4; ++mt)
#pragma unroll
      for (int i = 0; i < 2; ++i)
        pk[mt][i] = (unsigned)f2bf(p[mt * 4 + 2 * i] * inv) | ((unsigned)f2bf(p[mt * 4 + 2 * i + 1] * inv) << 16);

    f32x4 o2[2] = {zero, zero};
#pragma unroll
    for (int kk = 0; kk < 2; ++kk) {
      union { unsigned u[4]; short8 v; } pf;
#pragma unroll
      for (int i = 0; i < 2; ++i) {
        unsigned x0 = (unsigned)__shfl((int)pk[2 * kk][i], laneA, 64);
        unsigned x1 = (unsigned)__shfl((int)pk[2 * kk + 1][i], laneA, 64);
        unsigned y0 = (unsigned)__shfl((int)pk[2 * kk][i], laneA + 16, 64);
        unsigned y1 = (unsigned)__shfl((int)pk[2 * kk + 1][i], laneA + 16, 64);
        pf.u[i] = hi ? x1 : x0;
        pf.u[2 + i] = hi ? y1 : y0;
      }
      __builtin_amdgcn_s_setprio(1);
#pragma unroll
      for (int dt = 0; dt < 2; ++dt)
        o2[dt] = __builtin_amdgcn_mfma_f32_16x16x32_bf16(vfT[dt][kk], pf.v, o2[dt], 0, 0, 0);
      __builtin_amdgcn_s_setprio(0);
    }

    // store this nt's output immediately: D col = q = nt*16+cr, D row = d = dt*16+cg*4+reg
    int t = nt * 16 + cr;
    size_t row = base + ((t >> 3) << 6) + (t & 7);
#pragma unroll
    for (int dt = 0; dt < 2; ++dt) {
      uint2 pck;
      pck.x = (unsigned)f2bf(o2[dt][0]) | ((unsigned)f2bf(o2[dt][1]) << 16);
      pck.y = (unsigned)f2bf(o2[dt][2]) | ((unsigned)f2bf(o2[dt][3]) << 16);
      *(uint2*)(aout + row * 512 + head * 32 + dt * 16 + cg * 4) = pck;
    }
  }
}

// ---------------- launch (round-12 dataflow: nch=2 full pipeline, verified) ----------------
extern "C" void kernel_launch(void* const* d_in, const int* in_sizes, int n_in,
                              void* d_out, int out_size, void* d_ws, size_t ws_size,
                              hipStream_t stream) {
  const float* x = (const float*)d_in[0];
  const float* norm_g = (const float*)d_in[1];
  const float* norm_b = (const float*)d_in[2];
  const float* w_qkv = (const float*)d_in[3];
  const float* w_out = (const float*)d_in[4];
  const float* b_out = (const float*)d_in[5];
  const float* dw0 = (const float*)d_in[6];
  const float* db0 = (const float*)d_in[7];
  const float* dg0 = (const float*)d_in[8];
  const float* dw1 = (const float*)d_in[9];
  const float* db1 = (const float*)d_in[10];
  const float* dg1 = (const float*)d_in[11];
  const float* dw2 = (const float*)d_in[12];
  const float* db2 = (const float*)d_in[13];
  const float* dg2 = (const float*)d_in[14];
  const float* dw3 = (const float*)d_in[15];
  const float* db3 = (const float*)d_in[16];

  char* ws = (char*)d_ws;
  size_t off = 0;
  auto take = [&](size_t bytes) { char* p = ws + off; off += (bytes + 255) & ~(size_t)255; return p; };
  u16* xln = (u16*)take(65536ull * 512 * 2);
  u16* wqkvT = (u16*)take(1536 * 512 * 2);
  u16* woutT = (u16*)take(512 * 512 * 2);
  float* biases = (float*)take(289 * 4);
  float* table = (float*)take(4096 * 4);

  ln_cast_kernel<<<16384, 256, 0, stream>>>(x, norm_g, norm_b, xln);
  prep_w_kernel<<<4096, 256, 0, stream>>>(w_qkv, w_out, wqkvT, woutT);
  dpb_mlp_kernel<<<289, 128, 0, stream>>>(dw0, db0, dg0, dw1, db1, dg1, dw2, db2, dg2, dw3, db3, biases);
  dpb_table_kernel<<<16, 256, 0, stream>>>(biases, table);

  size_t rem = (ws_size > off) ? ws_size - off : 0;
  int nch = 4;
  if (rem >= 32768ull * 2048 * 2 + 512) nch = 2;
  const int rows = 65536 / nch;
  u16* qkvbuf = (u16*)take((size_t)rows * 1536 * 2);
  u16* attnbuf = (u16*)take((size_t)rows * 512 * 2);

  for (int c = 0; c < nch; ++c) {
    const u16* Ac = xln + (size_t)c * rows * 512;
    gemm_bk64_kernel<12, false><<<(rows / 128) * 12, 256, 0, stream>>>(Ac, wqkvT, (void*)qkvbuf, nullptr);
    attn_kernel<<<(rows / 64) * 16 / 4, 256, 0, stream>>>(qkvbuf, table, attnbuf);
    float* Cc = (float*)d_out + (size_t)c * rows * 512;
    gemm_bk64_kernel<4, true><<<(rows / 128) * 4, 256, 0, stream>>>(attnbuf, woutT, (void*)Cc, b_out);
  }
}

// Round 17
// 333.283 us; speedup vs baseline: 1.0724x; 1.0052x over previous
//
#include <hip/hip_runtime.h>
#include <cstdint>
#include <cstddef>

typedef unsigned short u16;
typedef __attribute__((ext_vector_type(8))) short short8;
typedef __attribute__((ext_vector_type(4))) float f32x4;
typedef __attribute__((ext_vector_type(4))) unsigned short us4;

#define AS1 __attribute__((address_space(1)))
#define AS3 __attribute__((address_space(3)))

__device__ __forceinline__ u16 f2bf(float f) {
  union { float f; unsigned u; } v; v.f = f;
  unsigned r = v.u + 0x7fffu + ((v.u >> 16) & 1u);
  return (u16)(r >> 16);
}

__device__ __forceinline__ void gload_lds16(const u16* g, u16* l) {
  __builtin_amdgcn_global_load_lds((AS1 void*)g, (AS3 void*)l, 16, 0, 0);
}

// ---------------- LayerNorm + cast to bf16 (token-major) ----------------
__global__ void ln_cast_kernel(const float* __restrict__ x, const float* __restrict__ g,
                               const float* __restrict__ b, u16* __restrict__ out) {
  const int lane = threadIdx.x & 63;
  const int tok = blockIdx.x * 4 + (threadIdx.x >> 6);
  const float4* row = (const float4*)(x + (size_t)tok * 512);
  float4 v0 = row[lane];
  float4 v1 = row[lane + 64];
  float s = v0.x + v0.y + v0.z + v0.w + v1.x + v1.y + v1.z + v1.w;
  float q = v0.x*v0.x + v0.y*v0.y + v0.z*v0.z + v0.w*v0.w
          + v1.x*v1.x + v1.y*v1.y + v1.z*v1.z + v1.w*v1.w;
#pragma unroll
  for (int m = 1; m < 64; m <<= 1) { s += __shfl_xor(s, m, 64); q += __shfl_xor(q, m, 64); }
  const float mean = s * (1.0f / 512.0f);
  const float var = q * (1.0f / 512.0f) - mean * mean;
  const float r = rsqrtf(var + 1e-5f);
  const float4* g4 = (const float4*)g;
  const float4* b4 = (const float4*)b;
  float4 ga = g4[lane], gb = g4[lane + 64];
  float4 ba = b4[lane], bb = b4[lane + 64];
  us4 o0 = { f2bf((v0.x - mean) * r * ga.x + ba.x), f2bf((v0.y - mean) * r * ga.y + ba.y),
             f2bf((v0.z - mean) * r * ga.z + ba.z), f2bf((v0.w - mean) * r * ga.w + ba.w) };
  us4 o1 = { f2bf((v1.x - mean) * r * gb.x + bb.x), f2bf((v1.y - mean) * r * gb.y + bb.y),
             f2bf((v1.z - mean) * r * gb.z + bb.z), f2bf((v1.w - mean) * r * gb.w + bb.w) };
  *(us4*)(out + (size_t)tok * 512 + lane * 4) = o0;
  *(us4*)(out + (size_t)tok * 512 + 256 + lane * 4) = o1;
}

// ---------------- weight transpose + cast ----------------
__global__ void prep_w_kernel(const float* __restrict__ wqkv, const float* __restrict__ wout,
                              u16* __restrict__ wqkvT, u16* __restrict__ woutT) {
  int idx = blockIdx.x * blockDim.x + threadIdx.x;
  if (idx < 512 * 1536) {
    int n = idx >> 9, k = idx & 511;
    wqkvT[idx] = f2bf(wqkv[k * 1536 + n]);
  } else {
    int j = idx - 512 * 1536;
    if (j < 512 * 512) {
      int n = j >> 9, k = j & 511;
      woutT[j] = f2bf(wout[k * 512 + n]);
    }
  }
}

// ---------------- DPB MLP ----------------
__device__ __forceinline__ float lnrelu128(float a, float g, float* red, int tid) {
  float s = a, q = a * a;
#pragma unroll
  for (int m = 1; m < 64; m <<= 1) { s += __shfl_xor(s, m, 64); q += __shfl_xor(q, m, 64); }
  __syncthreads();
  if ((tid & 63) == 0) { red[tid >> 6] = s; red[2 + (tid >> 6)] = q; }
  __syncthreads();
  float S = red[0] + red[1], Q = red[2] + red[3];
  float mean = S * (1.f / 128.f);
  float var = Q * (1.f / 128.f) - mean * mean;
  float y = (a - mean) * rsqrtf(var + 1e-5f) * g;
  return fmaxf(y, 0.f);
}

__global__ void dpb_mlp_kernel(const float* __restrict__ w0, const float* __restrict__ b0, const float* __restrict__ g0,
                               const float* __restrict__ w1, const float* __restrict__ b1, const float* __restrict__ g1,
                               const float* __restrict__ w2, const float* __restrict__ b2, const float* __restrict__ g2,
                               const float* __restrict__ w3, const float* __restrict__ b3,
                               float* __restrict__ biases) {
  __shared__ float h[128];
  __shared__ float red[4];
  const int tid = threadIdx.x;
  const int row = blockIdx.x;
  const float p0 = (float)(row / 17) - 8.0f;
  const float p1 = (float)(row % 17) - 8.0f;
  float a = p0 * w0[tid] + p1 * w0[128 + tid] + b0[tid];
  a = lnrelu128(a, g0[tid], red, tid);
  h[tid] = a;
  __syncthreads();
  float acc = b1[tid];
  for (int i = 0; i < 128; ++i) acc += h[i] * w1[i * 128 + tid];
  acc = lnrelu128(acc, g1[tid], red, tid);
  h[tid] = acc;
  __syncthreads();
  float acc2 = b2[tid];
  for (int i = 0; i < 128; ++i) acc2 += h[i] * w2[i * 128 + tid];
  acc2 = lnrelu128(acc2, g2[tid], red, tid);
  float t = acc2 * w3[tid];
#pragma unroll
  for (int m = 1; m < 64; m <<= 1) t += __shfl_xor(t, m, 64);
  __syncthreads();
  if ((tid & 63) == 0) red[tid >> 6] = t;
  __syncthreads();
  if (tid == 0) biases[row] = red[0] + red[1] + b3[0];
}

__global__ void dpb_table_kernel(const float* __restrict__ biases, float* __restrict__ table) {
  int t = blockIdx.x * blockDim.x + threadIdx.x;
  if (t < 4096) {
    int i = t >> 6, j = t & 63;
    int r0 = (i >> 3) - (j >> 3) + 7;
    int r1 = (i & 7) - (j & 7) + 7;
    table[t] = biases[r0 * 15 + r1];
  }
}

// ---------------- 128x128 bf16 GEMM, BK=64, 4 blocks/CU (round-10, verified) ----------------
template <int CT, bool F32OUT>
__global__ __launch_bounds__(256, 4) void gemm_bk64_kernel(const u16* __restrict__ A, const u16* __restrict__ BT,
                                                           void* __restrict__ Cv, const float* __restrict__ bias) {
  __shared__ __align__(16) u16 As[128 * 64];
  __shared__ __align__(16) u16 Bs[128 * 64];
  const int tid = threadIdx.x;
  const int w = tid >> 6, l = tid & 63;
  const int wr = w >> 1, wc = w & 1;
  const int cr = l & 15, cg = l >> 4;
  const int hcr = (cr + ((cr >> 3) << 2)) & 7;

  const int hw = blockIdx.x;
  const int ix = hw >> 3;
  const int rt = (hw & 7) + 8 * (ix / CT);
  const int ct = ix % CT;
  const size_t brow = (size_t)rt * 128;
  const size_t bcol = (size_t)ct * 128;
  const int N = CT * 128;

  const int srow8 = tid >> 3;
  const int hsrc = ((srow8 & 15) + (((srow8 >> 3) & 1) << 2)) & 7;
  const int csrc = ((tid & 7) ^ hsrc) * 8;
  const u16* gA = A + (brow + srow8) * 512 + csrc;
  const u16* gB = BT + (bcol + srow8) * 512 + csrc;

  const f32x4 zero = {0.f, 0.f, 0.f, 0.f};
  f32x4 acc[4][4];
#pragma unroll
  for (int i = 0; i < 4; ++i)
#pragma unroll
    for (int j = 0; j < 4; ++j) acc[i][j] = zero;

  const u16* aP = &As[(wr * 64 + cr) * 64];
  const u16* bP = &Bs[(wc * 64 + cr) * 64];

  for (int k0 = 0; k0 < 512; k0 += 64) {
#pragma unroll
    for (int j = 0; j < 4; ++j) {
      gload_lds16(gA + (size_t)j * 32 * 512 + k0, &As[j * 2048 + w * 512]);
      gload_lds16(gB + (size_t)j * 32 * 512 + k0, &Bs[j * 2048 + w * 512]);
    }
    __syncthreads();
#pragma unroll
    for (int ks = 0; ks < 2; ++ks) {
      short8 af[4], bf[4];
      const int pco = ((ks * 4 + cg) ^ hcr) * 8;
#pragma unroll
      for (int fr = 0; fr < 4; ++fr) af[fr] = *(const short8*)(aP + fr * 1024 + pco);
#pragma unroll
      for (int fc = 0; fc < 4; ++fc) bf[fc] = *(const short8*)(bP + fc * 1024 + pco);
#pragma unroll
      for (int fr = 0; fr < 4; ++fr)
#pragma unroll
        for (int fc = 0; fc < 4; ++fc)
          acc[fr][fc] = __builtin_amdgcn_mfma_f32_16x16x32_bf16(bf[fc], af[fr], acc[fr][fc], 0, 0, 0);
    }
    __syncthreads();
  }

  if (F32OUT) {
    float* C = (float*)Cv;
#pragma unroll
    for (int fc = 0; fc < 4; ++fc) {
      size_t col = bcol + wc * 64 + fc * 16 + cg * 4;
      float4 bv = *(const float4*)&bias[col];
#pragma unroll
      for (int fr = 0; fr < 4; ++fr) {
        size_t r = brow + wr * 64 + fr * 16 + cr;
        float4 o = { acc[fr][fc][0] + bv.x, acc[fr][fc][1] + bv.y,
                     acc[fr][fc][2] + bv.z, acc[fr][fc][3] + bv.w };
        *(float4*)(C + r * N + col) = o;
      }
    }
  } else {
    u16* C = (u16*)Cv;
#pragma unroll
    for (int fc = 0; fc < 4; ++fc) {
      size_t col = bcol + wc * 64 + fc * 16 + cg * 4;
#pragma unroll
      for (int fr = 0; fr < 4; ++fr) {
        size_t r = brow + wr * 64 + fr * 16 + cr;
        uint2 p;
        p.x = (unsigned)f2bf(acc[fr][fc][0]) | ((unsigned)f2bf(acc[fr][fc][1]) << 16);
        p.y = (unsigned)f2bf(acc[fr][fc][2]) | ((unsigned)f2bf(acc[fr][fc][3]) << 16);
        *(uint2*)(C + r * N + col) = p;
      }
    }
  }
}

// ---------------- windowed attention v4 @ 4 blocks/CU (round-17: occupancy A/B) ----------------
// Round-16's v4 is latency-bound: per-nt serial chain ~1300 cyc x4, only 3 waves/SIMD
// resident. Live set ~120 VGPR fits the 128 cap -> (256,4): 16 waves/CU (+33% TLP).
__global__ __launch_bounds__(256, 4) void attn_kernel(const u16* __restrict__ qkv,
                                                      const float* __restrict__ table,
                                                      u16* __restrict__ aout) {
  __shared__ __align__(16) u16 VT[4][32 * 74];
  const int l = threadIdx.x & 63;
  const int wv = threadIdx.x >> 6;
  const int pair = blockIdx.x * 4 + wv;
  const int head = pair & 15;
  const int win = pair >> 4;
  const int base = ((win >> 6) << 12) + (((win >> 3) & 7) << 9) + ((win & 7) << 3);
  const int cr = l & 15, cg = l >> 4;
  u16* vt = VT[wv];

  short8 qf[4], kf[4];
  {
    short8 vl[4];
#pragma unroll
    for (int i = 0; i < 4; ++i) {
      int t = i * 16 + cr;
      size_t row = base + ((t >> 3) << 6) + (t & 7);
      const u16* rp = qkv + row * 1536 + head * 32 + cg * 8;
      qf[i] = *(const short8*)(rp);
      kf[i] = *(const short8*)(rp + 512);
      vl[i] = *(const short8*)(rp + 1024);
    }
#pragma unroll
    for (int mt = 0; mt < 4; ++mt)
#pragma unroll
      for (int j = 0; j < 8; ++j)
        vt[(cg * 8 + j) * 74 + mt * 16 + cr] = (u16)vl[mt][j];
  }

  asm volatile("s_waitcnt lgkmcnt(0)" ::: "memory");
  __builtin_amdgcn_sched_barrier(0);
  short8 vfT[2][2];
#pragma unroll
  for (int dt = 0; dt < 2; ++dt)
#pragma unroll
    for (int kk = 0; kk < 2; ++kk)
      vfT[dt][kk] = *(const short8*)&vt[(dt * 16 + cr) * 74 + kk * 32 + cg * 8];

  const f32x4 zero = {0.f, 0.f, 0.f, 0.f};
  const float scale = 0.17677669529663689f;
  const int laneA = cr + 32 * (cg & 1);
  const int hi = cg >> 1;

#pragma unroll
  for (int nt = 0; nt < 4; ++nt) {
    f32x4 s4[4];
    __builtin_amdgcn_s_setprio(1);
#pragma unroll
    for (int mt = 0; mt < 4; ++mt)
      s4[mt] = __builtin_amdgcn_mfma_f32_16x16x32_bf16(kf[mt], qf[nt], zero, 0, 0, 0);
    __builtin_amdgcn_s_setprio(0);

    float p[16];
    float mx = -3.0e38f;
#pragma unroll
    for (int mt = 0; mt < 4; ++mt) {
      float4 tb = *(const float4*)&table[(nt * 16 + cr) * 64 + mt * 16 + cg * 4];
      p[mt * 4 + 0] = s4[mt][0] * scale + tb.x;
      p[mt * 4 + 1] = s4[mt][1] * scale + tb.y;
      p[mt * 4 + 2] = s4[mt][2] * scale + tb.z;
      p[mt * 4 + 3] = s4[mt][3] * scale + tb.w;
      mx = fmaxf(mx, fmaxf(fmaxf(p[mt * 4], p[mt * 4 + 1]), fmaxf(p[mt * 4 + 2], p[mt * 4 + 3])));
    }
    mx = fmaxf(mx, __shfl_xor(mx, 16, 64));
    mx = fmaxf(mx, __shfl_xor(mx, 32, 64));
    float sum = 0.f;
#pragma unroll
    for (int i = 0; i < 16; ++i) { p[i] = __expf(p[i] - mx); sum += p[i]; }
    sum += __shfl_xor(sum, 16, 64);
    sum += __shfl_xor(sum, 32, 64);
    const float inv = 1.0f / sum;

    unsigned pk[4][2];
#pragma unroll
    for (int mt = 0; mt < 4; ++mt)
#pragma unroll
      for (int i = 0; i < 2; ++i)
        pk[mt][i] = (unsigned)f2bf(p[mt * 4 + 2 * i] * inv) | ((unsigned)f2bf(p[mt * 4 + 2 * i + 1] * inv) << 16);

    f32x4 o2[2] = {zero, zero};
#pragma unroll
    for (int kk = 0; kk < 2; ++kk) {
      union { unsigned u[4]; short8 v; } pf;
#pragma unroll
      for (int i = 0; i < 2; ++i) {
        unsigned x0 = (unsigned)__shfl((int)pk[2 * kk][i], laneA, 64);
        unsigned x1 = (unsigned)__shfl((int)pk[2 * kk + 1][i], laneA, 64);
        unsigned y0 = (unsigned)__shfl((int)pk[2 * kk][i], laneA + 16, 64);
        unsigned y1 = (unsigned)__shfl((int)pk[2 * kk + 1][i], laneA + 16, 64);
        pf.u[i] = hi ? x1 : x0;
        pf.u[2 + i] = hi ? y1 : y0;
      }
      __builtin_amdgcn_s_setprio(1);
#pragma unroll
      for (int dt = 0; dt < 2; ++dt)
        o2[dt] = __builtin_amdgcn_mfma_f32_16x16x32_bf16(vfT[dt][kk], pf.v, o2[dt], 0, 0, 0);
      __builtin_amdgcn_s_setprio(0);
    }

    int t = nt * 16 + cr;
    size_t row = base + ((t >> 3) << 6) + (t & 7);
#pragma unroll
    for (int dt = 0; dt < 2; ++dt) {
      uint2 pck;
      pck.x = (unsigned)f2bf(o2[dt][0]) | ((unsigned)f2bf(o2[dt][1]) << 16);
      pck.y = (unsigned)f2bf(o2[dt][2]) | ((unsigned)f2bf(o2[dt][3]) << 16);
      *(uint2*)(aout + row * 512 + head * 32 + dt * 16 + cg * 4) = pck;
    }
  }
}

// ---------------- launch (round-12 dataflow: nch=2 full pipeline, verified) ----------------
extern "C" void kernel_launch(void* const* d_in, const int* in_sizes, int n_in,
                              void* d_out, int out_size, void* d_ws, size_t ws_size,
                              hipStream_t stream) {
  const float* x = (const float*)d_in[0];
  const float* norm_g = (const float*)d_in[1];
  const float* norm_b = (const float*)d_in[2];
  const float* w_qkv = (const float*)d_in[3];
  const float* w_out = (const float*)d_in[4];
  const float* b_out = (const float*)d_in[5];
  const float* dw0 = (const float*)d_in[6];
  const float* db0 = (const float*)d_in[7];
  const float* dg0 = (const float*)d_in[8];
  const float* dw1 = (const float*)d_in[9];
  const float* db1 = (const float*)d_in[10];
  const float* dg1 = (const float*)d_in[11];
  const float* dw2 = (const float*)d_in[12];
  const float* db2 = (const float*)d_in[13];
  const float* dg2 = (const float*)d_in[14];
  const float* dw3 = (const float*)d_in[15];
  const float* db3 = (const float*)d_in[16];

  char* ws = (char*)d_ws;
  size_t off = 0;
  auto take = [&](size_t bytes) { char* p = ws + off; off += (bytes + 255) & ~(size_t)255; return p; };
  u16* xln = (u16*)take(65536ull * 512 * 2);
  u16* wqkvT = (u16*)take(1536 * 512 * 2);
  u16* woutT = (u16*)take(512 * 512 * 2);
  float* biases = (float*)take(289 * 4);
  float* table = (float*)take(4096 * 4);

  ln_cast_kernel<<<16384, 256, 0, stream>>>(x, norm_g, norm_b, xln);
  prep_w_kernel<<<4096, 256, 0, stream>>>(w_qkv, w_out, wqkvT, woutT);
  dpb_mlp_kernel<<<289, 128, 0, stream>>>(dw0, db0, dg0, dw1, db1, dg1, dw2, db2, dg2, dw3, db3, biases);
  dpb_table_kernel<<<16, 256, 0, stream>>>(biases, table);

  size_t rem = (ws_size > off) ? ws_size - off : 0;
  int nch = 4;
  if (rem >= 32768ull * 2048 * 2 + 512) nch = 2;
  const int rows = 65536 / nch;
  u16* qkvbuf = (u16*)take((size_t)rows * 1536 * 2);
  u16* attnbuf = (u16*)take((size_t)rows * 512 * 2);

  for (int c = 0; c < nch; ++c) {
    const u16* Ac = xln + (size_t)c * rows * 512;
    gemm_bk64_kernel<12, false><<<(rows / 128) * 12, 256, 0, stream>>>(Ac, wqkvT, (void*)qkvbuf, nullptr);
    attn_kernel<<<(rows / 64) * 16 / 4, 256, 0, stream>>>(qkvbuf, table, attnbuf);
    float* Cc = (float*)d_out + (size_t)c * rows * 512;
    gemm_bk64_kernel<4, true><<<(rows / 128) * 4, 256, 0, stream>>>(attnbuf, woutT, (void*)Cc, b_out);
  }
}